// Round 10
// baseline (19016.814 us; speedup 1.0000x reference)
//
#include <hip/hip_runtime.h>
#include <math.h>

#define BATCH 1024
#define IN_F  1024
#define OUT_F 2048
#define LAMBD 0.2f
#define TOL   1e-4f
#define MAX_ITERS 100

#define KSPLIT 4
#define KCHUNK (OUT_F / KSPLIT)   // 512
#define NBLOCKS 512               // persistent grid: 2 blocks/CU on 256 CUs
#define BSCALE 32.0f
#define BSCALE_INV 0.03125f

typedef _Float16 half8 __attribute__((ext_vector_type(8)));
typedef _Float16 half4 __attribute__((ext_vector_type(4)));
typedef float    floatx16 __attribute__((ext_vector_type(16)));
typedef unsigned char fp8_t;

#define GLOAD_LDS16(g, l) __builtin_amdgcn_global_load_lds(              \
    (const __attribute__((address_space(1))) void*)(g),                  \
    (__attribute__((address_space(3))) void*)(l), 16, 0, 0)

// fp8 e4m3 (OCP on gfx950) HW converts
__device__ inline int pk4_fp8(float a, float b, float c, float d) {
    int w = __builtin_amdgcn_cvt_pk_fp8_f32(a, b, 0, false);
    w = __builtin_amdgcn_cvt_pk_fp8_f32(c, d, w, true);
    return w;
}
__device__ inline fp8_t enc_fp8(float a) {
    return (fp8_t)(__builtin_amdgcn_cvt_pk_fp8_f32(a, a, 0, false) & 0xff);
}
__device__ inline void cvt4_fp8(int w, float o[4]) {
    o[0] = __builtin_amdgcn_cvt_f32_fp8(w, 0);
    o[1] = __builtin_amdgcn_cvt_f32_fp8(w, 1);
    o[2] = __builtin_amdgcn_cvt_f32_fp8(w, 2);
    o[3] = __builtin_amdgcn_cvt_f32_fp8(w, 3);
}

// ---------------------------------------------------------------------------
// device-scope generation barrier (all NBLOCKS blocks co-resident by
// construction: 512 blocks, 16.6KB LDS, <=256 VGPR -> 2 blocks/CU).
// __threadfence() provides the agent-scope release/acquire (L2 wb/inv).
// ---------------------------------------------------------------------------
__device__ inline void grid_sync(int* cnt, int* gen) {
    __syncthreads();
    if (threadIdx.x == 0) {
        __threadfence();   // release: drain + write-back before arrival
        const int g = __hip_atomic_load(gen, __ATOMIC_RELAXED, __HIP_MEMORY_SCOPE_AGENT);
        if (__hip_atomic_fetch_add(cnt, 1, __ATOMIC_ACQ_REL, __HIP_MEMORY_SCOPE_AGENT)
            == NBLOCKS - 1) {
            __hip_atomic_store(cnt, 0, __ATOMIC_RELAXED, __HIP_MEMORY_SCOPE_AGENT);
            __hip_atomic_fetch_add(gen, 1, __ATOMIC_ACQ_REL, __HIP_MEMORY_SCOPE_AGENT);
        } else {
            while (__hip_atomic_load(gen, __ATOMIC_ACQUIRE, __HIP_MEMORY_SCOPE_AGENT) == g) {
                __builtin_amdgcn_s_sleep(2);
            }
        }
        __threadfence();   // acquire: invalidate stale L1/L2 before reads
    }
    __syncthreads();
}

// ---------------------------------------------------------------------------
// init: zero v,u (fp16), enc (fp32 out), solved flags, barrier state
// ---------------------------------------------------------------------------
__global__ void init_kernel(float4* __restrict__ v16, float4* __restrict__ u16,
                            float4* __restrict__ enc, int* __restrict__ solved,
                            int* __restrict__ bar) {
    const int i = blockIdx.x * blockDim.x + threadIdx.x;
    const float4 z = make_float4(0.f, 0.f, 0.f, 0.f);
    const int nh = BATCH * OUT_F / 8;
    const int n4 = BATCH * OUT_F / 4;
    if (i < nh) { v16[i] = z; u16[i] = z; }
    if (i < n4) enc[i] = z;
    if (i < BATCH) solved[i] = 0;
    if (i < 2) bar[i] = 0;
}

// ---------------------------------------------------------------------------
// elementwise fp32 -> fp16 cast (n multiple of 4)
// ---------------------------------------------------------------------------
__global__ __launch_bounds__(256)
void cast_f16_kernel(const float* __restrict__ in, _Float16* __restrict__ out, int n) {
    const int i = (blockIdx.x * 256 + threadIdx.x) * 4;
    if (i < n) {
        const float4 f = *(const float4*)&in[i];
        half4 h;
        h[0] = (_Float16)f.x; h[1] = (_Float16)f.y;
        h[2] = (_Float16)f.z; h[3] = (_Float16)f.w;
        *(half4*)&out[i] = h;
    }
}

// ---------------------------------------------------------------------------
// transpose + fp16 cast: W [OUT_F][IN_F] fp32 -> WT [IN_F][OUT_F] fp16
// ---------------------------------------------------------------------------
__global__ __launch_bounds__(256)
void transpose_w_kernel(const float* __restrict__ W, _Float16* __restrict__ WT) {
    __shared__ float tile[32][33];
    const int tid = threadIdx.x;
    const int row0 = blockIdx.y * 32;
    const int col0 = blockIdx.x * 32;
    const int r = tid >> 3;
    const int c4 = (tid & 7) * 4;
    const float4 b4 = *(const float4*)&W[(size_t)(row0 + r) * IN_F + col0 + c4];
    tile[r][c4 + 0] = b4.x; tile[r][c4 + 1] = b4.y;
    tile[r][c4 + 2] = b4.z; tile[r][c4 + 3] = b4.w;
    __syncthreads();
    half4 h;
#pragma unroll
    for (int j = 0; j < 4; ++j) h[j] = (_Float16)tile[c4 + j][r];
    *(half4*)&WT[(size_t)(col0 + r) * OUT_F + row0 + c4] = h;
}

// ---------------------------------------------------------------------------
// Transpose + fp8-cast (x32) M_inv (2048x2048 fp32 [k][n]) -> BhT fp8 [n][k].
// ---------------------------------------------------------------------------
__global__ __launch_bounds__(256)
void split_b_kernel(const float* __restrict__ B, fp8_t* __restrict__ BhT) {
    __shared__ float tile[32][33];
    const int tid = threadIdx.x;
    const int k0 = blockIdx.y * 32;
    const int n0 = blockIdx.x * 32;
    const int r = tid >> 3;
    const int c4 = (tid & 7) * 4;
    const float4 b4 = *(const float4*)&B[(size_t)(k0 + r) * OUT_F + n0 + c4];
    tile[r][c4 + 0] = b4.x; tile[r][c4 + 1] = b4.y;
    tile[r][c4 + 2] = b4.z; tile[r][c4 + 3] = b4.w;
    __syncthreads();
    const int w = pk4_fp8(tile[c4 + 0][r] * BSCALE, tile[c4 + 1][r] * BSCALE,
                          tile[c4 + 2][r] * BSCALE, tile[c4 + 3][r] * BSCALE);
    *(int*)&BhT[(size_t)(n0 + r) * OUT_F + k0 + c4] = w;
}

// ---------------------------------------------------------------------------
// fp16 MFMA NT GEMM (one-shot): C = A @ B^T -> Abh fp16 + Ah fp8.
// ---------------------------------------------------------------------------
__global__ __launch_bounds__(256)
void mfma_nt_ab(const _Float16* __restrict__ A, const _Float16* __restrict__ B,
                _Float16* __restrict__ Abh, fp8_t* __restrict__ Ah,
                int N, int K) {
    __shared__ _Float16 sA[128 * 32];
    __shared__ _Float16 sB[128 * 32];
    const int tid = threadIdx.x;
    const int m0 = blockIdx.y * 128;
    const int n0 = blockIdx.x * 128;
    const int wv = tid >> 6, ln = tid & 63;
    const int half = ln >> 5, l31 = ln & 31;
    const int wm = (wv >> 1) * 64, wn = (wv & 1) * 64;
    const int r0 = tid >> 2, koff = (tid & 3) * 8;
    const size_t ga0 = (size_t)(m0 + r0) * K + koff;
    const size_t ga1 = (size_t)(m0 + r0 + 64) * K + koff;
    const size_t gb0 = (size_t)(n0 + r0) * K + koff;
    const size_t gb1 = (size_t)(n0 + r0 + 64) * K + koff;
    const int ldst0 = tid * 8, ldst1 = (256 + tid) * 8;

    floatx16 acc[2][2];
#pragma unroll
    for (int a = 0; a < 2; ++a)
#pragma unroll
        for (int b = 0; b < 2; ++b)
#pragma unroll
            for (int q = 0; q < 16; ++q) acc[a][b][q] = 0.f;

    for (int k = 0; k < K; k += 32) {
        __syncthreads();
        GLOAD_LDS16(A + ga0 + k, sA + ldst0);
        GLOAD_LDS16(A + ga1 + k, sA + ldst1);
        GLOAD_LDS16(B + gb0 + k, sB + ldst0);
        GLOAD_LDS16(B + gb1 + k, sB + ldst1);
        __syncthreads();
#pragma unroll
        for (int kk = 0; kk < 2; ++kk) {
            const int ko = kk * 16 + half * 8;
            const half8 a0 = *(const half8*)&sA[(wm + l31) * 32 + ko];
            const half8 a1 = *(const half8*)&sA[(wm + 32 + l31) * 32 + ko];
            const half8 b0 = *(const half8*)&sB[(wn + l31) * 32 + ko];
            const half8 b1 = *(const half8*)&sB[(wn + 32 + l31) * 32 + ko];
            acc[0][0] = __builtin_amdgcn_mfma_f32_32x32x16_f16(a0, b0, acc[0][0], 0, 0, 0);
            acc[0][1] = __builtin_amdgcn_mfma_f32_32x32x16_f16(a0, b1, acc[0][1], 0, 0, 0);
            acc[1][0] = __builtin_amdgcn_mfma_f32_32x32x16_f16(a1, b0, acc[1][0], 0, 0, 0);
            acc[1][1] = __builtin_amdgcn_mfma_f32_32x32x16_f16(a1, b1, acc[1][1], 0, 0, 0);
        }
    }
#pragma unroll
    for (int mm = 0; mm < 2; ++mm)
#pragma unroll
        for (int nn = 0; nn < 2; ++nn) {
            const int col = n0 + wn + nn * 32 + l31;
#pragma unroll
            for (int q = 0; q < 16; ++q) {
                const int row = m0 + wm + mm * 32 + (q & 3) + 8 * (q >> 2) + 4 * half;
                const size_t o = (size_t)row * N + col;
                const float x = acc[mm][nn][q];
                Abh[o] = (_Float16)x;
                Ah[o] = enc_fp8(x);
            }
        }
}

// ---------------------------------------------------------------------------
// fp16 MFMA NT GEMM (one-shot): dec = enc @ w via A=ench, B=whT (both K-major)
// ---------------------------------------------------------------------------
__global__ __launch_bounds__(256)
void mfma_nn_dec(const _Float16* __restrict__ A, const _Float16* __restrict__ B,
                 float* __restrict__ C, int N, int K) {
    __shared__ _Float16 sA[128 * 32];
    __shared__ _Float16 sB[128 * 32];
    const int tid = threadIdx.x;
    const int m0 = blockIdx.y * 128;
    const int n0 = blockIdx.x * 128;
    const int wv = tid >> 6, ln = tid & 63;
    const int half = ln >> 5, l31 = ln & 31;
    const int wm = (wv >> 1) * 64, wn = (wv & 1) * 64;
    const int r0 = tid >> 2, koff = (tid & 3) * 8;
    const size_t ga0 = (size_t)(m0 + r0) * K + koff;
    const size_t ga1 = (size_t)(m0 + r0 + 64) * K + koff;
    const size_t gb0 = (size_t)(n0 + r0) * K + koff;
    const size_t gb1 = (size_t)(n0 + r0 + 64) * K + koff;
    const int ldst0 = tid * 8, ldst1 = (256 + tid) * 8;

    floatx16 acc[2][2];
#pragma unroll
    for (int a = 0; a < 2; ++a)
#pragma unroll
        for (int b = 0; b < 2; ++b)
#pragma unroll
            for (int q = 0; q < 16; ++q) acc[a][b][q] = 0.f;

    for (int k = 0; k < K; k += 32) {
        __syncthreads();
        GLOAD_LDS16(A + ga0 + k, sA + ldst0);
        GLOAD_LDS16(A + ga1 + k, sA + ldst1);
        GLOAD_LDS16(B + gb0 + k, sB + ldst0);
        GLOAD_LDS16(B + gb1 + k, sB + ldst1);
        __syncthreads();
#pragma unroll
        for (int kk = 0; kk < 2; ++kk) {
            const int ko = kk * 16 + half * 8;
            const half8 a0 = *(const half8*)&sA[(wm + l31) * 32 + ko];
            const half8 a1 = *(const half8*)&sA[(wm + 32 + l31) * 32 + ko];
            const half8 b0 = *(const half8*)&sB[(wn + l31) * 32 + ko];
            const half8 b1 = *(const half8*)&sB[(wn + 32 + l31) * 32 + ko];
            acc[0][0] = __builtin_amdgcn_mfma_f32_32x32x16_f16(a0, b0, acc[0][0], 0, 0, 0);
            acc[0][1] = __builtin_amdgcn_mfma_f32_32x32x16_f16(a0, b1, acc[0][1], 0, 0, 0);
            acc[1][0] = __builtin_amdgcn_mfma_f32_32x32x16_f16(a1, b0, acc[1][0], 0, 0, 0);
            acc[1][1] = __builtin_amdgcn_mfma_f32_32x32x16_f16(a1, b1, acc[1][1], 0, 0, 0);
        }
    }
#pragma unroll
    for (int mm = 0; mm < 2; ++mm)
#pragma unroll
        for (int nn = 0; nn < 2; ++nn) {
            const int col = n0 + wn + nn * 32 + l31;
#pragma unroll
            for (int q = 0; q < 16; ++q) {
                const int row = m0 + wm + mm * 32 + (q & 3) + 8 * (q >> 2) + 4 * half;
                C[(size_t)row * N + col] = acc[mm][nn][q];
            }
        }
}

// ---------------------------------------------------------------------------
// Persistent fused ADMM loop: 512 blocks, 100 iterations in ONE dispatch.
// Per iter: fp8 MFMA GEMM tile (mi,ni,kz as R8) -> grid barrier ->
// update (2 rows/block) -> grid barrier. Replaces 200 dispatches.
// ---------------------------------------------------------------------------
__global__ __launch_bounds__(256, 2)
void admm_persist(const fp8_t* __restrict__ BhT, fp8_t* __restrict__ Ah,
                  fp8_t* __restrict__ xkp, const _Float16* __restrict__ Abh,
                  _Float16* __restrict__ v, _Float16* __restrict__ u,
                  float* __restrict__ enc, int* __restrict__ solved,
                  int* __restrict__ bar) {
    __shared__ fp8_t smem[16384];
    fp8_t* sA = smem;
    fp8_t* sB = smem + 8192;
    __shared__ float sdx[4], sxn[4];
    __shared__ float s_conv;
    __shared__ int s_active;
    constexpr size_t P = (size_t)BATCH * OUT_F;

    const int tid = threadIdx.x;
    const int bid = blockIdx.x;
    const int ni = bid & 15, mi = (bid >> 4) & 7, kz = bid >> 7;
    const int m0 = mi * 128, n0 = ni * 128;

    const int wv = tid >> 6, ln = tid & 63;
    const int half = ln >> 5, l31 = ln & 31;
    const int wm = (wv >> 1) * 64, wn = (wv & 1) * 64;

    // GEMM staging (loop-invariant addressing)
    const int r = tid & 127;
    const int c0 = tid >> 7;
    const fp8_t* gA = Ah  + (size_t)(m0 + r) * OUT_F + kz * KCHUNK;
    const fp8_t* gB = BhT + (size_t)(n0 + r) * OUT_F + kz * KCHUNK;
    fp8_t* lA0 = sA + (c0 * 128 + r) * 16;
    fp8_t* lA1 = sA + ((c0 + 2) * 128 + r) * 16;
    fp8_t* lB0 = sB + (c0 * 128 + r) * 16;
    fp8_t* lB1 = sB + ((c0 + 2) * 128 + r) * 16;
    const int ao0 = (wm + l31) * 16 + half * 8;
    const int ao1 = (wm + 32 + l31) * 16 + half * 8;
    const int bo0 = (wn + l31) * 16 + half * 8;
    const int bo1 = (wn + 32 + l31) * 16 + half * 8;
    fp8_t* outp = xkp + kz * P + (size_t)m0 * OUT_F + n0;

    int* bcnt = bar;
    int* bgen = bar + 1;

    for (int it = 0; it < MAX_ITERS; ++it) {
        // ================= phase 1: GEMM partial for tile (mi,ni,kz) ======
        if (tid == 0) s_active = 0;
        __syncthreads();
        if (tid < 128 && solved[m0 + tid] == 0) s_active = 1;   // benign race
        __syncthreads();
        if (s_active) {
            floatx16 acc[2][2];
#pragma unroll
            for (int a = 0; a < 2; ++a)
#pragma unroll
                for (int b = 0; b < 2; ++b)
#pragma unroll
                    for (int q = 0; q < 16; ++q) acc[a][b][q] = 0.f;

            for (int k = 0; k < KCHUNK; k += 64) {
                __syncthreads();
                GLOAD_LDS16(gA + k + c0 * 16, lA0);
                GLOAD_LDS16(gA + k + (c0 + 2) * 16, lA1);
                GLOAD_LDS16(gB + k + c0 * 16, lB0);
                GLOAD_LDS16(gB + k + (c0 + 2) * 16, lB1);
                __syncthreads();
#pragma unroll
                for (int kk = 0; kk < 4; ++kk) {
                    const int cb = kk * 2048;
                    const long long a0 = *(const long long*)&sA[cb + ao0];
                    const long long a1 = *(const long long*)&sA[cb + ao1];
                    const long long b0 = *(const long long*)&sB[cb + bo0];
                    const long long b1 = *(const long long*)&sB[cb + bo1];
                    acc[0][0] = __builtin_amdgcn_mfma_f32_32x32x16_fp8_fp8(a0, b0, acc[0][0], 0, 0, 0);
                    acc[0][1] = __builtin_amdgcn_mfma_f32_32x32x16_fp8_fp8(a0, b1, acc[0][1], 0, 0, 0);
                    acc[1][0] = __builtin_amdgcn_mfma_f32_32x32x16_fp8_fp8(a1, b0, acc[1][0], 0, 0, 0);
                    acc[1][1] = __builtin_amdgcn_mfma_f32_32x32x16_fp8_fp8(a1, b1, acc[1][1], 0, 0, 0);
                }
            }
            // epilogue: LDS transpose -> coalesced 16B stores
            __syncthreads();
#pragma unroll
            for (int mm = 0; mm < 2; ++mm)
#pragma unroll
                for (int nn = 0; nn < 2; ++nn) {
                    const int lcol = wn + nn * 32 + l31;
#pragma unroll
                    for (int q = 0; q < 16; ++q) {
                        const int lrow = wm + mm * 32 + (q & 3) + 8 * (q >> 2) + 4 * half;
                        smem[lrow * 128 + lcol] = enc_fp8(acc[mm][nn][q] * BSCALE_INV);
                    }
                }
            __syncthreads();
#pragma unroll
            for (int s = 0; s < 4; ++s) {
                const int f = (s * 256 + tid) * 16;
                *(int4*)&outp[(size_t)(f >> 7) * OUT_F + (f & 127)] = *(const int4*)&smem[f];
            }
        }
        grid_sync(bcnt, bgen);

        // ================= phase 2: update rows 2*bid, 2*bid+1 ============
#pragma unroll
        for (int rr = 0; rr < 2; ++rr) {
            const int row = bid * 2 + rr;
            if (!solved[row]) {                 // block-uniform branch
                const int c = tid * 8;
                const size_t off = (size_t)row * OUT_F + c;
                const int2 q0 = *(const int2*)&xkp[off];
                const int2 q1 = *(const int2*)&xkp[P + off];
                const int2 q2 = *(const int2*)&xkp[2 * P + off];
                const int2 q3 = *(const int2*)&xkp[3 * P + off];
                const half8 u8 = *(const half8*)&u[off];
                const half8 v8 = *(const half8*)&v[off];
                const half8 ab8 = *(const half8*)&Abh[off];

                float f0[4], f1[4], f2[4], f3[4], g0[4], g1[4], g2[4], g3[4];
                cvt4_fp8(q0.x, f0); cvt4_fp8(q1.x, f1); cvt4_fp8(q2.x, f2); cvt4_fp8(q3.x, f3);
                cvt4_fp8(q0.y, g0); cvt4_fp8(q1.y, g1); cvt4_fp8(q2.y, g2); cvt4_fp8(q3.y, g3);
                float xs[8];
#pragma unroll
                for (int j = 0; j < 4; ++j) {
                    xs[j] = f0[j] + f1[j] + f2[j] + f3[j];
                    xs[j + 4] = g0[j] + g1[j] + g2[j] + g3[j];
                }

                float vn_all[8], ae[8];
                half8 vo, uo;
                float dx2 = 0.f, xn2 = 0.f;
#pragma unroll
                for (int j = 0; j < 8; ++j) {
                    const float xk = xs[j];
                    const float uv = (float)u8[j];
                    const float vp = (float)v8[j];
                    const float z = xk + uv;
                    const float az = fabsf(z) - LAMBD;
                    const float vnew = az > 0.f ? copysignf(az, z) : 0.f;
                    const float unew = uv + xk - vnew;
                    const float d = vnew - vp;
                    dx2 += d * d;
                    xn2 += vnew * vnew;
                    vn_all[j] = vnew;
                    vo[j] = (_Float16)vnew;
                    uo[j] = (_Float16)unew;
                    ae[j] = (float)ab8[j] + vnew - unew;
                }
                *(half8*)&v[off] = vo;
                *(half8*)&u[off] = uo;
                int2 ah;
                ah.x = pk4_fp8(ae[0], ae[1], ae[2], ae[3]);
                ah.y = pk4_fp8(ae[4], ae[5], ae[6], ae[7]);
                *(int2*)&Ah[off] = ah;

#pragma unroll
                for (int o = 32; o > 0; o >>= 1) {
                    dx2 += __shfl_down(dx2, o);
                    xn2 += __shfl_down(xn2, o);
                }
                if ((tid & 63) == 0) { sdx[tid >> 6] = dx2; sxn[tid >> 6] = xn2; }
                __syncthreads();
                if (tid == 0) {
                    const float dxt = sqrtf(sdx[0] + sdx[1] + sdx[2] + sdx[3]);
                    const float xnt = sqrtf(sxn[0] + sxn[1] + sxn[2] + sxn[3]);
                    const bool conv = (dxt / xnt) < TOL;   // NaN -> false
                    s_conv = conv ? 1.f : 0.f;
                    if (conv) solved[row] = 1;
                }
                __syncthreads();
                if (s_conv != 0.f) {
                    *(float4*)&enc[off] = make_float4(vn_all[0], vn_all[1], vn_all[2], vn_all[3]);
                    *(float4*)&enc[off + 4] = make_float4(vn_all[4], vn_all[5], vn_all[6], vn_all[7]);
                }
                __syncthreads();
            }
        }
        grid_sync(bcnt, bgen);
    }
}

// ---------------------------------------------------------------------------
extern "C" void kernel_launch(void* const* d_in, const int* in_sizes, int n_in,
                              void* d_out, int out_size, void* d_ws, size_t ws_size,
                              hipStream_t stream) {
    (void)in_sizes; (void)n_in; (void)out_size; (void)ws_size;
    const float* x    = (const float*)d_in[0];   // 1024 x 1024
    const float* w    = (const float*)d_in[1];   // 2048 x 1024
    const float* Minv = (const float*)d_in[2];   // 2048 x 2048

    float* enc = (float*)d_out;                  // 1024 x 2048
    float* dec = enc + (size_t)BATCH * OUT_F;    // 1024 x 1024

    constexpr size_t P = (size_t)BATCH * OUT_F;  // 2M elements
    _Float16* Abh = (_Float16*)d_ws;             // P f16
    _Float16* v   = Abh + P;                     // P f16
    _Float16* u   = v + P;                       // P f16
    _Float16* xh  = u + P;                       // 1M f16
    _Float16* wh  = xh + (size_t)BATCH * IN_F;   // 2M f16
    _Float16* whT = wh + (size_t)OUT_F * IN_F;   // 2M f16
    _Float16* ench = whT + (size_t)IN_F * OUT_F; // P f16
    fp8_t* Ah  = (fp8_t*)(ench + P);             // P fp8
    fp8_t* xkp = Ah + P;                         // 4P fp8
    fp8_t* BhT = xkp + 4 * P;                    // OUT_F^2 fp8 (4MB)
    int* solved = (int*)(BhT + (size_t)OUT_F * OUT_F);
    int* bar = solved + BATCH;                   // 2 ints: count, generation

    {
        const int n = BATCH * OUT_F / 4;
        init_kernel<<<(n + 255) / 256, 256, 0, stream>>>(
            (float4*)v, (float4*)u, (float4*)enc, solved, bar);
    }

    split_b_kernel<<<dim3(OUT_F / 32, OUT_F / 32), 256, 0, stream>>>(Minv, BhT);

    cast_f16_kernel<<<(BATCH * IN_F / 4 + 255) / 256, 256, 0, stream>>>(x, xh, BATCH * IN_F);
    cast_f16_kernel<<<(OUT_F * IN_F / 4 + 255) / 256, 256, 0, stream>>>(w, wh, OUT_F * IN_F);
    transpose_w_kernel<<<dim3(IN_F / 32, OUT_F / 32), 256, 0, stream>>>(w, whT);

    mfma_nt_ab<<<dim3(OUT_F / 128, BATCH / 128), 256, 0, stream>>>(
        xh, wh, Abh, Ah, OUT_F, IN_F);

    // the whole 100-iteration ADMM loop: ONE dispatch
    admm_persist<<<NBLOCKS, 256, 0, stream>>>(BhT, Ah, xkp, Abh, v, u, enc,
                                              solved, bar);

    cast_f16_kernel<<<(BATCH * OUT_F / 4 + 255) / 256, 256, 0, stream>>>(enc, ench, BATCH * OUT_F);
    mfma_nn_dec<<<dim3(IN_F / 128, BATCH / 128), 256, 0, stream>>>(
        ench, whT, dec, IN_F, OUT_F);
}

// Round 11
// 6886.175 us; speedup vs baseline: 2.7616x; 2.7616x over previous
//
#include <hip/hip_runtime.h>
#include <math.h>

#define BATCH 1024
#define IN_F  1024
#define OUT_F 2048
#define LAMBD 0.2f
#define TOL   1e-4f
#define MAX_ITERS 100

#define KSPLIT 4
#define KCHUNK (OUT_F / KSPLIT)   // 512
#define BSCALE 32.0f
#define BSCALE_INV 0.03125f

typedef _Float16 half8 __attribute__((ext_vector_type(8)));
typedef _Float16 half4 __attribute__((ext_vector_type(4)));
typedef float    floatx16 __attribute__((ext_vector_type(16)));
typedef unsigned char fp8_t;

#define GLOAD_LDS16(g, l) __builtin_amdgcn_global_load_lds(              \
    (const __attribute__((address_space(1))) void*)(g),                  \
    (__attribute__((address_space(3))) void*)(l), 16, 0, 0)

__device__ inline int pk4_fp8(float a, float b, float c, float d) {
    int w = __builtin_amdgcn_cvt_pk_fp8_f32(a, b, 0, false);
    w = __builtin_amdgcn_cvt_pk_fp8_f32(c, d, w, true);
    return w;
}
__device__ inline fp8_t enc_fp8(float a) {
    return (fp8_t)(__builtin_amdgcn_cvt_pk_fp8_f32(a, a, 0, false) & 0xff);
}
__device__ inline void cvt4_fp8(int w, float o[4]) {
    o[0] = __builtin_amdgcn_cvt_f32_fp8(w, 0);
    o[1] = __builtin_amdgcn_cvt_f32_fp8(w, 1);
    o[2] = __builtin_amdgcn_cvt_f32_fp8(w, 2);
    o[3] = __builtin_amdgcn_cvt_f32_fp8(w, 3);
}

// ---------------------------------------------------------------------------
__global__ void init_kernel(float4* __restrict__ v16, float4* __restrict__ u16,
                            float4* __restrict__ enc, int* __restrict__ solved,
                            int* __restrict__ cnt) {
    const int i = blockIdx.x * blockDim.x + threadIdx.x;
    const float4 z = make_float4(0.f, 0.f, 0.f, 0.f);
    const int nh = BATCH * OUT_F / 8;
    const int n4 = BATCH * OUT_F / 4;
    if (i < nh) { v16[i] = z; u16[i] = z; }
    if (i < n4) enc[i] = z;
    if (i < BATCH) solved[i] = -1;        // -1 = unsolved; else step index
    if (i < 128) cnt[i] = 0;
}

// ---------------------------------------------------------------------------
__global__ __launch_bounds__(256)
void cast_f16_kernel(const float* __restrict__ in, _Float16* __restrict__ out, int n) {
    const int i = (blockIdx.x * 256 + threadIdx.x) * 4;
    if (i < n) {
        const float4 f = *(const float4*)&in[i];
        half4 h;
        h[0] = (_Float16)f.x; h[1] = (_Float16)f.y;
        h[2] = (_Float16)f.z; h[3] = (_Float16)f.w;
        *(half4*)&out[i] = h;
    }
}

// ---------------------------------------------------------------------------
__global__ __launch_bounds__(256)
void transpose_w_kernel(const float* __restrict__ W, _Float16* __restrict__ WT) {
    __shared__ float tile[32][33];
    const int tid = threadIdx.x;
    const int row0 = blockIdx.y * 32;
    const int col0 = blockIdx.x * 32;
    const int r = tid >> 3;
    const int c4 = (tid & 7) * 4;
    const float4 b4 = *(const float4*)&W[(size_t)(row0 + r) * IN_F + col0 + c4];
    tile[r][c4 + 0] = b4.x; tile[r][c4 + 1] = b4.y;
    tile[r][c4 + 2] = b4.z; tile[r][c4 + 3] = b4.w;
    __syncthreads();
    half4 h;
#pragma unroll
    for (int j = 0; j < 4; ++j) h[j] = (_Float16)tile[c4 + j][r];
    *(half4*)&WT[(size_t)(col0 + r) * OUT_F + row0 + c4] = h;
}

// ---------------------------------------------------------------------------
__global__ __launch_bounds__(256)
void split_b_kernel(const float* __restrict__ B, fp8_t* __restrict__ BhT) {
    __shared__ float tile[32][33];
    const int tid = threadIdx.x;
    const int k0 = blockIdx.y * 32;
    const int n0 = blockIdx.x * 32;
    const int r = tid >> 3;
    const int c4 = (tid & 7) * 4;
    const float4 b4 = *(const float4*)&B[(size_t)(k0 + r) * OUT_F + n0 + c4];
    tile[r][c4 + 0] = b4.x; tile[r][c4 + 1] = b4.y;
    tile[r][c4 + 2] = b4.z; tile[r][c4 + 3] = b4.w;
    __syncthreads();
    const int w = pk4_fp8(tile[c4 + 0][r] * BSCALE, tile[c4 + 1][r] * BSCALE,
                          tile[c4 + 2][r] * BSCALE, tile[c4 + 3][r] * BSCALE);
    *(int*)&BhT[(size_t)(n0 + r) * OUT_F + k0 + c4] = w;
}

// ---------------------------------------------------------------------------
__global__ __launch_bounds__(256)
void mfma_nt_ab(const _Float16* __restrict__ A, const _Float16* __restrict__ B,
                _Float16* __restrict__ Abh, fp8_t* __restrict__ Ah,
                int N, int K) {
    __shared__ _Float16 sA[128 * 32];
    __shared__ _Float16 sB[128 * 32];
    const int tid = threadIdx.x;
    const int m0 = blockIdx.y * 128;
    const int n0 = blockIdx.x * 128;
    const int wv = tid >> 6, ln = tid & 63;
    const int half = ln >> 5, l31 = ln & 31;
    const int wm = (wv >> 1) * 64, wn = (wv & 1) * 64;
    const int r0 = tid >> 2, koff = (tid & 3) * 8;
    const size_t ga0 = (size_t)(m0 + r0) * K + koff;
    const size_t ga1 = (size_t)(m0 + r0 + 64) * K + koff;
    const size_t gb0 = (size_t)(n0 + r0) * K + koff;
    const size_t gb1 = (size_t)(n0 + r0 + 64) * K + koff;
    const int ldst0 = tid * 8, ldst1 = (256 + tid) * 8;

    floatx16 acc[2][2];
#pragma unroll
    for (int a = 0; a < 2; ++a)
#pragma unroll
        for (int b = 0; b < 2; ++b)
#pragma unroll
            for (int q = 0; q < 16; ++q) acc[a][b][q] = 0.f;

    for (int k = 0; k < K; k += 32) {
        __syncthreads();
        GLOAD_LDS16(A + ga0 + k, sA + ldst0);
        GLOAD_LDS16(A + ga1 + k, sA + ldst1);
        GLOAD_LDS16(B + gb0 + k, sB + ldst0);
        GLOAD_LDS16(B + gb1 + k, sB + ldst1);
        __syncthreads();
#pragma unroll
        for (int kk = 0; kk < 2; ++kk) {
            const int ko = kk * 16 + half * 8;
            const half8 a0 = *(const half8*)&sA[(wm + l31) * 32 + ko];
            const half8 a1 = *(const half8*)&sA[(wm + 32 + l31) * 32 + ko];
            const half8 b0 = *(const half8*)&sB[(wn + l31) * 32 + ko];
            const half8 b1 = *(const half8*)&sB[(wn + 32 + l31) * 32 + ko];
            acc[0][0] = __builtin_amdgcn_mfma_f32_32x32x16_f16(a0, b0, acc[0][0], 0, 0, 0);
            acc[0][1] = __builtin_amdgcn_mfma_f32_32x32x16_f16(a0, b1, acc[0][1], 0, 0, 0);
            acc[1][0] = __builtin_amdgcn_mfma_f32_32x32x16_f16(a1, b0, acc[1][0], 0, 0, 0);
            acc[1][1] = __builtin_amdgcn_mfma_f32_32x32x16_f16(a1, b1, acc[1][1], 0, 0, 0);
        }
    }
#pragma unroll
    for (int mm = 0; mm < 2; ++mm)
#pragma unroll
        for (int nn = 0; nn < 2; ++nn) {
            const int col = n0 + wn + nn * 32 + l31;
#pragma unroll
            for (int q = 0; q < 16; ++q) {
                const int row = m0 + wm + mm * 32 + (q & 3) + 8 * (q >> 2) + 4 * half;
                const size_t o = (size_t)row * N + col;
                const float x = acc[mm][nn][q];
                Abh[o] = (_Float16)x;
                Ah[o] = enc_fp8(x);
            }
        }
}

// ---------------------------------------------------------------------------
__global__ __launch_bounds__(256)
void mfma_nn_dec(const _Float16* __restrict__ A, const _Float16* __restrict__ B,
                 float* __restrict__ C, int N, int K) {
    __shared__ _Float16 sA[128 * 32];
    __shared__ _Float16 sB[128 * 32];
    const int tid = threadIdx.x;
    const int m0 = blockIdx.y * 128;
    const int n0 = blockIdx.x * 128;
    const int wv = tid >> 6, ln = tid & 63;
    const int half = ln >> 5, l31 = ln & 31;
    const int wm = (wv >> 1) * 64, wn = (wv & 1) * 64;
    const int r0 = tid >> 2, koff = (tid & 3) * 8;
    const size_t ga0 = (size_t)(m0 + r0) * K + koff;
    const size_t ga1 = (size_t)(m0 + r0 + 64) * K + koff;
    const size_t gb0 = (size_t)(n0 + r0) * K + koff;
    const size_t gb1 = (size_t)(n0 + r0 + 64) * K + koff;
    const int ldst0 = tid * 8, ldst1 = (256 + tid) * 8;

    floatx16 acc[2][2];
#pragma unroll
    for (int a = 0; a < 2; ++a)
#pragma unroll
        for (int b = 0; b < 2; ++b)
#pragma unroll
            for (int q = 0; q < 16; ++q) acc[a][b][q] = 0.f;

    for (int k = 0; k < K; k += 32) {
        __syncthreads();
        GLOAD_LDS16(A + ga0 + k, sA + ldst0);
        GLOAD_LDS16(A + ga1 + k, sA + ldst1);
        GLOAD_LDS16(B + gb0 + k, sB + ldst0);
        GLOAD_LDS16(B + gb1 + k, sB + ldst1);
        __syncthreads();
#pragma unroll
        for (int kk = 0; kk < 2; ++kk) {
            const int ko = kk * 16 + half * 8;
            const half8 a0 = *(const half8*)&sA[(wm + l31) * 32 + ko];
            const half8 a1 = *(const half8*)&sA[(wm + 32 + l31) * 32 + ko];
            const half8 b0 = *(const half8*)&sB[(wn + l31) * 32 + ko];
            const half8 b1 = *(const half8*)&sB[(wn + 32 + l31) * 32 + ko];
            acc[0][0] = __builtin_amdgcn_mfma_f32_32x32x16_f16(a0, b0, acc[0][0], 0, 0, 0);
            acc[0][1] = __builtin_amdgcn_mfma_f32_32x32x16_f16(a0, b1, acc[0][1], 0, 0, 0);
            acc[1][0] = __builtin_amdgcn_mfma_f32_32x32x16_f16(a1, b0, acc[1][0], 0, 0, 0);
            acc[1][1] = __builtin_amdgcn_mfma_f32_32x32x16_f16(a1, b1, acc[1][1], 0, 0, 0);
        }
    }
#pragma unroll
    for (int mm = 0; mm < 2; ++mm)
#pragma unroll
        for (int nn = 0; nn < 2; ++nn) {
            const int col = n0 + wn + nn * 32 + l31;
#pragma unroll
            for (int q = 0; q < 16; ++q) {
                const int row = m0 + wm + mm * 32 + (q & 3) + 8 * (q >> 2) + 4 * half;
                C[(size_t)row * N + col] = acc[mm][nn][q];
            }
        }
}

// ---------------------------------------------------------------------------
// Fused ADMM step, dispatch d (0..100):
//  phase U (d>=1, t=d-1): each block updates its 32x128 patch (rows
//    mi*128+kz*32.., cols ni*128..) using xkp_r (prev dispatch), with
//    pipelined conv(t-1) from pdx_r/pxn_r; writes pdx_w/pxn_w; bumps
//    per-patch counter (release).
//  phase G (do_gemm): wait (relaxed spin, 4 local flags) until A-panel's 4
//    patches reach 4*d, acquire fence, fp8 MFMA GEMM -> xkp_w.
// 512 blocks, all co-resident (launch_bounds(256,2), 16.6KB LDS) -> spins safe.
// ---------------------------------------------------------------------------
__global__ __launch_bounds__(256, 2)
void admm_step(int d, int do_gemm,
               const fp8_t* __restrict__ BhT, fp8_t* __restrict__ Ah,
               fp8_t* __restrict__ xkp_w, const fp8_t* __restrict__ xkp_r,
               const _Float16* __restrict__ Abh, _Float16* __restrict__ v,
               _Float16* __restrict__ u, float* __restrict__ enc,
               int* __restrict__ solved, int* __restrict__ cnt,
               float* __restrict__ pdx_w, float* __restrict__ pxn_w,
               const float* __restrict__ pdx_r, const float* __restrict__ pxn_r) {
    __shared__ fp8_t smem[16384];
    fp8_t* sA = smem;
    fp8_t* sB = smem + 8192;
    __shared__ int s_active;
    constexpr size_t P = (size_t)BATCH * OUT_F;

    const int tid = threadIdx.x;
    const int bid = blockIdx.x;
    const int ni = bid & 15, mi = (bid >> 4) & 7, kz = bid >> 7;
    const int m0 = mi * 128, n0 = ni * 128;
    const int ln = tid & 63;

    // ======================= phase U: update (t = d-1) ======================
    if (d >= 1) {
        const int t = d - 1;
        const int row = m0 + kz * 32 + (tid >> 3);
        const int co = n0 + (tid & 7) * 16;
        const size_t off = (size_t)row * OUT_F + co;

        const int s = solved[row];
        bool conv = false;
        if (t >= 1) {
            float sd = 0.f, sn = 0.f;
            if ((tid & 7) == 0) {
#pragma unroll
                for (int q = 0; q < 16; ++q) {
                    sd += pdx_r[q * BATCH + row];
                    sn += pxn_r[q * BATCH + row];
                }
            }
            const int base = ln & ~7;
            sd = __shfl(sd, base);
            sn = __shfl(sn, base);
            conv = (sqrtf(sd) / sqrtf(sn)) < TOL;   // NaN -> false
        }
        const bool newly = conv && (s == -1 || s == t - 1);
        if (newly) {
            if ((tid & 7) == 0) solved[row] = t - 1;   // idempotent
            const half8 va = *(const half8*)&v[off];
            const half8 vb = *(const half8*)&v[off + 8];
            float4 e0, e1, e2, e3;
            e0 = make_float4((float)va[0], (float)va[1], (float)va[2], (float)va[3]);
            e1 = make_float4((float)va[4], (float)va[5], (float)va[6], (float)va[7]);
            e2 = make_float4((float)vb[0], (float)vb[1], (float)vb[2], (float)vb[3]);
            e3 = make_float4((float)vb[4], (float)vb[5], (float)vb[6], (float)vb[7]);
            *(float4*)&enc[off] = e0;  *(float4*)&enc[off + 4] = e1;
            *(float4*)&enc[off + 8] = e2; *(float4*)&enc[off + 12] = e3;
        }
        const bool frozen = (s != -1) || newly;
        if (!frozen) {
            const int4 q0 = *(const int4*)&xkp_r[off];
            const int4 q1 = *(const int4*)&xkp_r[P + off];
            const int4 q2 = *(const int4*)&xkp_r[2 * P + off];
            const int4 q3 = *(const int4*)&xkp_r[3 * P + off];
            const half8 va = *(const half8*)&v[off];
            const half8 vb = *(const half8*)&v[off + 8];
            const half8 ua = *(const half8*)&u[off];
            const half8 ub = *(const half8*)&u[off + 8];
            const half8 aa = *(const half8*)&Abh[off];
            const half8 ab = *(const half8*)&Abh[off + 8];
            const int w0[4] = {q0.x, q0.y, q0.z, q0.w};
            const int w1[4] = {q1.x, q1.y, q1.z, q1.w};
            const int w2[4] = {q2.x, q2.y, q2.z, q2.w};
            const int w3[4] = {q3.x, q3.y, q3.z, q3.w};
            half8 vo[2], uo[2];
            int aw[4];
            float dx2 = 0.f, xn2 = 0.f;
#pragma unroll
            for (int g = 0; g < 4; ++g) {
                float a0[4], a1[4], a2[4], a3[4], ae4[4];
                cvt4_fp8(w0[g], a0); cvt4_fp8(w1[g], a1);
                cvt4_fp8(w2[g], a2); cvt4_fp8(w3[g], a3);
#pragma unroll
                for (int j = 0; j < 4; ++j) {
                    const int idx = g * 4 + j;
                    const float xk = a0[j] + a1[j] + a2[j] + a3[j];
                    const float uv = (float)((idx < 8) ? ua[idx] : ub[idx - 8]);
                    const float vp = (float)((idx < 8) ? va[idx] : vb[idx - 8]);
                    const float z = xk + uv;
                    const float az = fabsf(z) - LAMBD;
                    const float vnew = az > 0.f ? copysignf(az, z) : 0.f;
                    const float unew = uv + xk - vnew;
                    const float dd = vnew - vp;
                    dx2 += dd * dd;
                    xn2 += vnew * vnew;
                    if (idx < 8) { vo[0][idx] = (_Float16)vnew; uo[0][idx] = (_Float16)unew; }
                    else { vo[1][idx - 8] = (_Float16)vnew; uo[1][idx - 8] = (_Float16)unew; }
                    ae4[j] = (float)((idx < 8) ? aa[idx] : ab[idx - 8]) + vnew - unew;
                }
                aw[g] = pk4_fp8(ae4[0], ae4[1], ae4[2], ae4[3]);
            }
            *(half8*)&v[off] = vo[0]; *(half8*)&v[off + 8] = vo[1];
            *(half8*)&u[off] = uo[0]; *(half8*)&u[off + 8] = uo[1];
            *(int4*)&Ah[off] = make_int4(aw[0], aw[1], aw[2], aw[3]);
            // 8-lane row reduction
            dx2 += __shfl_xor(dx2, 1); dx2 += __shfl_xor(dx2, 2); dx2 += __shfl_xor(dx2, 4);
            xn2 += __shfl_xor(xn2, 1); xn2 += __shfl_xor(xn2, 2); xn2 += __shfl_xor(xn2, 4);
            if ((tid & 7) == 0) {
                pdx_w[ni * BATCH + row] = dx2;
                pxn_w[ni * BATCH + row] = xn2;
            }
        }
        __syncthreads();
        if (tid == 0) {
            __threadfence();
            __hip_atomic_fetch_add(&cnt[mi * 16 + ni], 1,
                                   __ATOMIC_RELEASE, __HIP_MEMORY_SCOPE_AGENT);
        }
    }

    if (!do_gemm) return;

    // ======================= phase G: fp8 MFMA GEMM =========================
    if (d >= 1) {
        if (tid == 0) {
            const int target = 4 * d;
#pragma unroll
            for (int q = 0; q < 4; ++q) {
                int* f = &cnt[mi * 16 + kz * 4 + q];
                while (__hip_atomic_load(f, __ATOMIC_RELAXED,
                                         __HIP_MEMORY_SCOPE_AGENT) < target) {
                    __builtin_amdgcn_s_sleep(4);
                }
            }
            __threadfence();   // acquire: see peers' Ah writes
        }
        __syncthreads();
    }

    if (tid == 0) s_active = 0;
    __syncthreads();
    if (tid < 128 && solved[m0 + tid] == -1) s_active = 1;   // benign race
    __syncthreads();
    if (!s_active) return;

    const int wv = tid >> 6;
    const int half = ln >> 5;
    const int l31 = ln & 31;
    const int wm = (wv >> 1) * 64;
    const int wn = (wv & 1) * 64;

    const int r = tid & 127;
    const int c0 = tid >> 7;
    const fp8_t* gA = Ah  + (size_t)(m0 + r) * OUT_F + kz * KCHUNK;
    const fp8_t* gB = BhT + (size_t)(n0 + r) * OUT_F + kz * KCHUNK;
    fp8_t* lA0 = sA + (c0 * 128 + r) * 16;
    fp8_t* lA1 = sA + ((c0 + 2) * 128 + r) * 16;
    fp8_t* lB0 = sB + (c0 * 128 + r) * 16;
    fp8_t* lB1 = sB + ((c0 + 2) * 128 + r) * 16;

    floatx16 acc[2][2];
#pragma unroll
    for (int a = 0; a < 2; ++a)
#pragma unroll
        for (int b = 0; b < 2; ++b)
#pragma unroll
            for (int q = 0; q < 16; ++q) acc[a][b][q] = 0.f;

    const int ao0 = (wm + l31) * 16 + half * 8;
    const int ao1 = (wm + 32 + l31) * 16 + half * 8;
    const int bo0 = (wn + l31) * 16 + half * 8;
    const int bo1 = (wn + 32 + l31) * 16 + half * 8;

    for (int k = 0; k < KCHUNK; k += 64) {
        __syncthreads();
        GLOAD_LDS16(gA + k + c0 * 16, lA0);
        GLOAD_LDS16(gA + k + (c0 + 2) * 16, lA1);
        GLOAD_LDS16(gB + k + c0 * 16, lB0);
        GLOAD_LDS16(gB + k + (c0 + 2) * 16, lB1);
        __syncthreads();
#pragma unroll
        for (int kk = 0; kk < 4; ++kk) {
            const int cb = kk * 2048;
            const long long a0 = *(const long long*)&sA[cb + ao0];
            const long long a1 = *(const long long*)&sA[cb + ao1];
            const long long b0 = *(const long long*)&sB[cb + bo0];
            const long long b1 = *(const long long*)&sB[cb + bo1];
            acc[0][0] = __builtin_amdgcn_mfma_f32_32x32x16_fp8_fp8(a0, b0, acc[0][0], 0, 0, 0);
            acc[0][1] = __builtin_amdgcn_mfma_f32_32x32x16_fp8_fp8(a0, b1, acc[0][1], 0, 0, 0);
            acc[1][0] = __builtin_amdgcn_mfma_f32_32x32x16_fp8_fp8(a1, b0, acc[1][0], 0, 0, 0);
            acc[1][1] = __builtin_amdgcn_mfma_f32_32x32x16_fp8_fp8(a1, b1, acc[1][1], 0, 0, 0);
        }
    }

    __syncthreads();
#pragma unroll
    for (int mm = 0; mm < 2; ++mm)
#pragma unroll
        for (int nn = 0; nn < 2; ++nn) {
            const int lcol = wn + nn * 32 + l31;
#pragma unroll
            for (int q = 0; q < 16; ++q) {
                const int lrow = wm + mm * 32 + (q & 3) + 8 * (q >> 2) + 4 * half;
                smem[lrow * 128 + lcol] = enc_fp8(acc[mm][nn][q] * BSCALE_INV);
            }
        }
    __syncthreads();
    fp8_t* outp = xkp_w + (size_t)kz * P + (size_t)m0 * OUT_F + n0;
#pragma unroll
    for (int s = 0; s < 4; ++s) {
        const int f = (s * 256 + tid) * 16;
        *(int4*)&outp[(size_t)(f >> 7) * OUT_F + (f & 127)] = *(const int4*)&smem[f];
    }
}

// ---------------------------------------------------------------------------
// Final convergence check for step 99 (pipelined conv lags one dispatch).
// ---------------------------------------------------------------------------
__global__ __launch_bounds__(256)
void final_conv(const float* __restrict__ pdx, const float* __restrict__ pxn,
                const _Float16* __restrict__ v, const int* __restrict__ solved,
                float* __restrict__ enc) {
    const int row = blockIdx.x;
    __shared__ float ssd, ssn;
    if (threadIdx.x == 0) {
        float sd = 0.f, sn = 0.f;
        for (int q = 0; q < 16; ++q) {
            sd += pdx[q * BATCH + row];
            sn += pxn[q * BATCH + row];
        }
        ssd = sd; ssn = sn;
    }
    __syncthreads();
    if (solved[row] == -1 && (sqrtf(ssd) / sqrtf(ssn)) < TOL) {
        const size_t base = (size_t)row * OUT_F;
        for (int c = threadIdx.x * 8; c < OUT_F; c += 2048) {
            const half8 vv = *(const half8*)&v[base + c];
            *(float4*)&enc[base + c] =
                make_float4((float)vv[0], (float)vv[1], (float)vv[2], (float)vv[3]);
            *(float4*)&enc[base + c + 4] =
                make_float4((float)vv[4], (float)vv[5], (float)vv[6], (float)vv[7]);
        }
    }
}

// ---------------------------------------------------------------------------
extern "C" void kernel_launch(void* const* d_in, const int* in_sizes, int n_in,
                              void* d_out, int out_size, void* d_ws, size_t ws_size,
                              hipStream_t stream) {
    (void)in_sizes; (void)n_in; (void)out_size; (void)ws_size;
    const float* x    = (const float*)d_in[0];   // 1024 x 1024
    const float* w    = (const float*)d_in[1];   // 2048 x 1024
    const float* Minv = (const float*)d_in[2];   // 2048 x 2048

    float* enc = (float*)d_out;                  // 1024 x 2048
    float* dec = enc + (size_t)BATCH * OUT_F;    // 1024 x 1024

    constexpr size_t P = (size_t)BATCH * OUT_F;  // 2M elements
    _Float16* Abh = (_Float16*)d_ws;             // P f16
    _Float16* v   = Abh + P;
    _Float16* u   = v + P;
    _Float16* xh  = u + P;                       // 1M f16
    _Float16* wh  = xh + (size_t)BATCH * IN_F;   // 2M f16 (reused as ench)
    _Float16* whT = wh + (size_t)OUT_F * IN_F;   // 2M f16
    fp8_t* Ah   = (fp8_t*)(whT + (size_t)IN_F * OUT_F);  // P fp8
    fp8_t* xkpA = Ah + P;                        // 4P fp8
    fp8_t* xkpB = xkpA + 4 * P;                  // 4P fp8
    fp8_t* BhT  = xkpB + 4 * P;                  // 4MB fp8
    float* pdx0 = (float*)(BhT + (size_t)OUT_F * OUT_F);  // 16x1024
    float* pxn0 = pdx0 + 16 * BATCH;
    float* pdx1 = pxn0 + 16 * BATCH;
    float* pxn1 = pdx1 + 16 * BATCH;
    int* solved = (int*)(pxn1 + 16 * BATCH);
    int* cnt = solved + BATCH;                   // 128 patch counters

    {
        const int n = BATCH * OUT_F / 4;
        init_kernel<<<(n + 255) / 256, 256, 0, stream>>>(
            (float4*)v, (float4*)u, (float4*)enc, solved, cnt);
    }

    split_b_kernel<<<dim3(OUT_F / 32, OUT_F / 32), 256, 0, stream>>>(Minv, BhT);
    cast_f16_kernel<<<(BATCH * IN_F / 4 + 255) / 256, 256, 0, stream>>>(x, xh, BATCH * IN_F);
    transpose_w_kernel<<<dim3(IN_F / 32, OUT_F / 32), 256, 0, stream>>>(w, whT);
    // wh as fp16 of w for NT GEMM (K-major): cast AFTER transpose kernel reads w? both read-only, order free
    cast_f16_kernel<<<(OUT_F * IN_F / 4 + 255) / 256, 256, 0, stream>>>(w, wh + 0, OUT_F * IN_F);

    // NOTE: wh doubles as ench later; use it for mfma_nt_ab FIRST.
    mfma_nt_ab<<<dim3(OUT_F / 128, BATCH / 128), 256, 0, stream>>>(
        xh, wh, Abh, Ah, OUT_F, IN_F);

    // fused loop: dispatch d = U(d-1) + G(d)
    for (int d = 0; d < MAX_ITERS; ++d) {
        fp8_t* xw = (d & 1) ? xkpB : xkpA;
        fp8_t* xr = (d & 1) ? xkpA : xkpB;
        const int t = d - 1;
        float* pw_dx = (t >= 0 && (t & 1)) ? pdx1 : pdx0;
        float* pw_xn = (t >= 0 && (t & 1)) ? pxn1 : pxn0;
        const float* pr_dx = (t >= 1 && ((t - 1) & 1)) ? pdx1 : pdx0;
        const float* pr_xn = (t >= 1 && ((t - 1) & 1)) ? pxn1 : pxn0;
        admm_step<<<512, 256, 0, stream>>>(d, 1, BhT, Ah, xw, xr, Abh, v, u, enc,
                                           solved, cnt, pw_dx, pw_xn, pr_dx, pr_xn);
    }
    // trailing update U(99), no GEMM  (d=100, t=99: writes pdx parity 1)
    {
        const int d = MAX_ITERS;
        fp8_t* xw = (d & 1) ? xkpB : xkpA;
        fp8_t* xr = (d & 1) ? xkpA : xkpB;
        admm_step<<<512, 256, 0, stream>>>(d, 0, BhT, Ah, xw, xr, Abh, v, u, enc,
                                           solved, cnt, pdx1, pxn1, pdx0, pxn0);
    }
    // conv(99) + enc emit
    final_conv<<<BATCH, 256, 0, stream>>>(pdx1, pxn1, v, solved, enc);

    // decoded = encoded @ w  (wh reused as ench)
    _Float16* ench = wh;
    cast_f16_kernel<<<(BATCH * OUT_F / 4 + 255) / 256, 256, 0, stream>>>(enc, ench, BATCH * OUT_F);
    mfma_nn_dec<<<dim3(IN_F / 128, BATCH / 128), 256, 0, stream>>>(
        ench, whT, dec, IN_F, OUT_F);
}

// Round 12
// 2607.808 us; speedup vs baseline: 7.2923x; 2.6406x over previous
//
#include <hip/hip_runtime.h>
#include <math.h>

#define BATCH 1024
#define IN_F  1024
#define OUT_F 2048
#define LAMBD 0.2f
#define TOL   1e-4f
#define MAX_ITERS 100

#define KSPLIT 4
#define KCHUNK (OUT_F / KSPLIT)   // 512
#define BSCALE 32.0f
#define BSCALE_INV 0.03125f

typedef _Float16 half8 __attribute__((ext_vector_type(8)));
typedef _Float16 half4 __attribute__((ext_vector_type(4)));
typedef float    floatx16 __attribute__((ext_vector_type(16)));
typedef unsigned char fp8_t;

#define GLOAD_LDS16(g, l) __builtin_amdgcn_global_load_lds(              \
    (const __attribute__((address_space(1))) void*)(g),                  \
    (__attribute__((address_space(3))) void*)(l), 16, 0, 0)

// fp8 e4m3 (OCP on gfx950) HW converts
__device__ inline int pk4_fp8(float a, float b, float c, float d) {
    int w = __builtin_amdgcn_cvt_pk_fp8_f32(a, b, 0, false);
    w = __builtin_amdgcn_cvt_pk_fp8_f32(c, d, w, true);
    return w;
}
__device__ inline fp8_t enc_fp8(float a) {
    return (fp8_t)(__builtin_amdgcn_cvt_pk_fp8_f32(a, a, 0, false) & 0xff);
}
// byte-selector must be a literal constant -> expand all four
__device__ inline void cvt4_fp8(int w, float o[4]) {
    o[0] = __builtin_amdgcn_cvt_f32_fp8(w, 0);
    o[1] = __builtin_amdgcn_cvt_f32_fp8(w, 1);
    o[2] = __builtin_amdgcn_cvt_f32_fp8(w, 2);
    o[3] = __builtin_amdgcn_cvt_f32_fp8(w, 3);
}

// ---------------------------------------------------------------------------
// init: zero v,u (fp16), enc (fp32 out), solved flags
// ---------------------------------------------------------------------------
__global__ void init_kernel(float4* __restrict__ v16, float4* __restrict__ u16,
                            float4* __restrict__ enc, int* __restrict__ solved) {
    const int i = blockIdx.x * blockDim.x + threadIdx.x;
    const float4 z = make_float4(0.f, 0.f, 0.f, 0.f);
    const int nh = BATCH * OUT_F / 8;
    const int n4 = BATCH * OUT_F / 4;
    if (i < nh) { v16[i] = z; u16[i] = z; }
    if (i < n4) enc[i] = z;
    if (i < BATCH) solved[i] = 0;
}

// ---------------------------------------------------------------------------
__global__ __launch_bounds__(256)
void cast_f16_kernel(const float* __restrict__ in, _Float16* __restrict__ out, int n) {
    const int i = (blockIdx.x * 256 + threadIdx.x) * 4;
    if (i < n) {
        const float4 f = *(const float4*)&in[i];
        half4 h;
        h[0] = (_Float16)f.x; h[1] = (_Float16)f.y;
        h[2] = (_Float16)f.z; h[3] = (_Float16)f.w;
        *(half4*)&out[i] = h;
    }
}

// ---------------------------------------------------------------------------
__global__ __launch_bounds__(256)
void transpose_w_kernel(const float* __restrict__ W, _Float16* __restrict__ WT) {
    __shared__ float tile[32][33];
    const int tid = threadIdx.x;
    const int row0 = blockIdx.y * 32;
    const int col0 = blockIdx.x * 32;
    const int r = tid >> 3;
    const int c4 = (tid & 7) * 4;
    const float4 b4 = *(const float4*)&W[(size_t)(row0 + r) * IN_F + col0 + c4];
    tile[r][c4 + 0] = b4.x; tile[r][c4 + 1] = b4.y;
    tile[r][c4 + 2] = b4.z; tile[r][c4 + 3] = b4.w;
    __syncthreads();
    half4 h;
#pragma unroll
    for (int j = 0; j < 4; ++j) h[j] = (_Float16)tile[c4 + j][r];
    *(half4*)&WT[(size_t)(col0 + r) * OUT_F + row0 + c4] = h;
}

// ---------------------------------------------------------------------------
// Transpose + fp8-cast (x32) M_inv (2048x2048 fp32 [k][n]) -> BhT fp8 [n][k].
// ---------------------------------------------------------------------------
__global__ __launch_bounds__(256)
void split_b_kernel(const float* __restrict__ B, fp8_t* __restrict__ BhT) {
    __shared__ float tile[32][33];
    const int tid = threadIdx.x;
    const int k0 = blockIdx.y * 32;
    const int n0 = blockIdx.x * 32;
    const int r = tid >> 3;
    const int c4 = (tid & 7) * 4;
    const float4 b4 = *(const float4*)&B[(size_t)(k0 + r) * OUT_F + n0 + c4];
    tile[r][c4 + 0] = b4.x; tile[r][c4 + 1] = b4.y;
    tile[r][c4 + 2] = b4.z; tile[r][c4 + 3] = b4.w;
    __syncthreads();
    const int w = pk4_fp8(tile[c4 + 0][r] * BSCALE, tile[c4 + 1][r] * BSCALE,
                          tile[c4 + 2][r] * BSCALE, tile[c4 + 3][r] * BSCALE);
    *(int*)&BhT[(size_t)(n0 + r) * OUT_F + k0 + c4] = w;
}

// ---------------------------------------------------------------------------
// fp16 MFMA NT GEMM (one-shot): Ab = x @ w^T -> Ab8 fp8 (persistent) +
// initial Aeff fp8 (identical, v=u=0). 128x128 tile, BK=32.
// ---------------------------------------------------------------------------
__global__ __launch_bounds__(256)
void mfma_nt_ab(const _Float16* __restrict__ A, const _Float16* __restrict__ B,
                fp8_t* __restrict__ Ab8, fp8_t* __restrict__ Ah,
                int N, int K) {
    __shared__ _Float16 sA[128 * 32];
    __shared__ _Float16 sB[128 * 32];
    const int tid = threadIdx.x;
    const int m0 = blockIdx.y * 128;
    const int n0 = blockIdx.x * 128;
    const int wv = tid >> 6, ln = tid & 63;
    const int half = ln >> 5, l31 = ln & 31;
    const int wm = (wv >> 1) * 64, wn = (wv & 1) * 64;
    const int r0 = tid >> 2, koff = (tid & 3) * 8;
    const size_t ga0 = (size_t)(m0 + r0) * K + koff;
    const size_t ga1 = (size_t)(m0 + r0 + 64) * K + koff;
    const size_t gb0 = (size_t)(n0 + r0) * K + koff;
    const size_t gb1 = (size_t)(n0 + r0 + 64) * K + koff;
    const int ldst0 = tid * 8, ldst1 = (256 + tid) * 8;

    floatx16 acc[2][2];
#pragma unroll
    for (int a = 0; a < 2; ++a)
#pragma unroll
        for (int b = 0; b < 2; ++b)
#pragma unroll
            for (int q = 0; q < 16; ++q) acc[a][b][q] = 0.f;

    for (int k = 0; k < K; k += 32) {
        __syncthreads();
        GLOAD_LDS16(A + ga0 + k, sA + ldst0);
        GLOAD_LDS16(A + ga1 + k, sA + ldst1);
        GLOAD_LDS16(B + gb0 + k, sB + ldst0);
        GLOAD_LDS16(B + gb1 + k, sB + ldst1);
        __syncthreads();
#pragma unroll
        for (int kk = 0; kk < 2; ++kk) {
            const int ko = kk * 16 + half * 8;
            const half8 a0 = *(const half8*)&sA[(wm + l31) * 32 + ko];
            const half8 a1 = *(const half8*)&sA[(wm + 32 + l31) * 32 + ko];
            const half8 b0 = *(const half8*)&sB[(wn + l31) * 32 + ko];
            const half8 b1 = *(const half8*)&sB[(wn + 32 + l31) * 32 + ko];
            acc[0][0] = __builtin_amdgcn_mfma_f32_32x32x16_f16(a0, b0, acc[0][0], 0, 0, 0);
            acc[0][1] = __builtin_amdgcn_mfma_f32_32x32x16_f16(a0, b1, acc[0][1], 0, 0, 0);
            acc[1][0] = __builtin_amdgcn_mfma_f32_32x32x16_f16(a1, b0, acc[1][0], 0, 0, 0);
            acc[1][1] = __builtin_amdgcn_mfma_f32_32x32x16_f16(a1, b1, acc[1][1], 0, 0, 0);
        }
    }
#pragma unroll
    for (int mm = 0; mm < 2; ++mm)
#pragma unroll
        for (int nn = 0; nn < 2; ++nn) {
            const int col = n0 + wn + nn * 32 + l31;
#pragma unroll
            for (int q = 0; q < 16; ++q) {
                const int row = m0 + wm + mm * 32 + (q & 3) + 8 * (q >> 2) + 4 * half;
                const size_t o = (size_t)row * N + col;
                const fp8_t e = enc_fp8(acc[mm][nn][q]);
                Ab8[o] = e;
                Ah[o] = e;     // initial Aeff (v=u=0)
            }
        }
}

// ---------------------------------------------------------------------------
// fp16 MFMA NT GEMM (one-shot): dec = enc @ w via A=ench, B=whT (both K-major)
// ---------------------------------------------------------------------------
__global__ __launch_bounds__(256)
void mfma_nn_dec(const _Float16* __restrict__ A, const _Float16* __restrict__ B,
                 float* __restrict__ C, int N, int K) {
    __shared__ _Float16 sA[128 * 32];
    __shared__ _Float16 sB[128 * 32];
    const int tid = threadIdx.x;
    const int m0 = blockIdx.y * 128;
    const int n0 = blockIdx.x * 128;
    const int wv = tid >> 6, ln = tid & 63;
    const int half = ln >> 5, l31 = ln & 31;
    const int wm = (wv >> 1) * 64, wn = (wv & 1) * 64;
    const int r0 = tid >> 2, koff = (tid & 3) * 8;
    const size_t ga0 = (size_t)(m0 + r0) * K + koff;
    const size_t ga1 = (size_t)(m0 + r0 + 64) * K + koff;
    const size_t gb0 = (size_t)(n0 + r0) * K + koff;
    const size_t gb1 = (size_t)(n0 + r0 + 64) * K + koff;
    const int ldst0 = tid * 8, ldst1 = (256 + tid) * 8;

    floatx16 acc[2][2];
#pragma unroll
    for (int a = 0; a < 2; ++a)
#pragma unroll
        for (int b = 0; b < 2; ++b)
#pragma unroll
            for (int q = 0; q < 16; ++q) acc[a][b][q] = 0.f;

    for (int k = 0; k < K; k += 32) {
        __syncthreads();
        GLOAD_LDS16(A + ga0 + k, sA + ldst0);
        GLOAD_LDS16(A + ga1 + k, sA + ldst1);
        GLOAD_LDS16(B + gb0 + k, sB + ldst0);
        GLOAD_LDS16(B + gb1 + k, sB + ldst1);
        __syncthreads();
#pragma unroll
        for (int kk = 0; kk < 2; ++kk) {
            const int ko = kk * 16 + half * 8;
            const half8 a0 = *(const half8*)&sA[(wm + l31) * 32 + ko];
            const half8 a1 = *(const half8*)&sA[(wm + 32 + l31) * 32 + ko];
            const half8 b0 = *(const half8*)&sB[(wn + l31) * 32 + ko];
            const half8 b1 = *(const half8*)&sB[(wn + 32 + l31) * 32 + ko];
            acc[0][0] = __builtin_amdgcn_mfma_f32_32x32x16_f16(a0, b0, acc[0][0], 0, 0, 0);
            acc[0][1] = __builtin_amdgcn_mfma_f32_32x32x16_f16(a0, b1, acc[0][1], 0, 0, 0);
            acc[1][0] = __builtin_amdgcn_mfma_f32_32x32x16_f16(a1, b0, acc[1][0], 0, 0, 0);
            acc[1][1] = __builtin_amdgcn_mfma_f32_32x32x16_f16(a1, b1, acc[1][1], 0, 0, 0);
        }
    }
#pragma unroll
    for (int mm = 0; mm < 2; ++mm)
#pragma unroll
        for (int nn = 0; nn < 2; ++nn) {
            const int col = n0 + wn + nn * 32 + l31;
#pragma unroll
            for (int q = 0; q < 16; ++q) {
                const int row = m0 + wm + mm * 32 + (q & 3) + 8 * (q >> 2) + 4 * half;
                C[(size_t)row * N + col] = acc[mm][nn][q];
            }
        }
}

// ---------------------------------------------------------------------------
// fp8 MFMA GEMM: xk_part[kz] = Aeff[:, kz*512...] @ (32*Minv)[kz...] / 32.
// 64x128 tile, BK=64, grid (16,16,4) = 1024 blocks = 4 blocks/CU (12KB LDS,
// ~90 VGPR) -- doubled occupancy vs R8's 128-tile for latency hiding.
// Column-chunk LDS layout (conflict-free); LDS-transpose epilogue (reuses sB)
// for coalesced 16B xkp stores.
// ---------------------------------------------------------------------------
__global__ __launch_bounds__(256)
void xk_mfma(const fp8_t* __restrict__ Ah, const fp8_t* __restrict__ BhT,
             fp8_t* __restrict__ xkp, const int* __restrict__ solved) {
    __shared__ fp8_t sA[64 * 64];     // 4KB
    __shared__ fp8_t sB[128 * 64];    // 8KB (reused as epilogue tile)
    const int tid = threadIdx.x;
    const int m0 = blockIdx.y * 64;
    const int n0 = blockIdx.x * 128;
    const int kz = blockIdx.z;
    constexpr size_t P = (size_t)BATCH * OUT_F;

    __shared__ int s_active;
    if (tid == 0) s_active = 0;
    __syncthreads();
    if (tid < 64 && solved[m0 + tid] == 0) s_active = 1;   // benign race
    __syncthreads();
    if (!s_active) return;

    const int wv = tid >> 6, ln = tid & 63;
    const int half = ln >> 5, l31 = ln & 31;
    const int wm = (wv >> 1) * 32;    // wave row base within 64
    const int wn = (wv & 1) * 64;     // wave col base within 128

    // A staging: 64x64 fp8, one 16B issue/thread: chunk = tid>>6, row = tid&63
    const int ar = tid & 63, ac = tid >> 6;
    const fp8_t* gA = Ah + (size_t)(m0 + ar) * OUT_F + kz * KCHUNK + ac * 16;
    fp8_t* lA = sA + (ac * 64 + ar) * 16;
    // B staging: 128x64 fp8, two issues: chunk = (i*2)+(tid>>7), row = tid&127
    const int br = tid & 127, bc0 = tid >> 7;
    const fp8_t* gB = BhT + (size_t)(n0 + br) * OUT_F + kz * KCHUNK;
    fp8_t* lB0 = sB + (bc0 * 128 + br) * 16;
    fp8_t* lB1 = sB + ((bc0 + 2) * 128 + br) * 16;

    floatx16 acc[2];
#pragma unroll
    for (int b = 0; b < 2; ++b)
#pragma unroll
        for (int q = 0; q < 16; ++q) acc[b][q] = 0.f;

    for (int k = 0; k < KCHUNK; k += 64) {
        __syncthreads();
        GLOAD_LDS16(gA + k, lA);
        GLOAD_LDS16(gB + k + bc0 * 16, lB0);
        GLOAD_LDS16(gB + k + (bc0 + 2) * 16, lB1);
        __syncthreads();
#pragma unroll
        for (int kk = 0; kk < 4; ++kk) {
            const long long a0 = *(const long long*)&sA[(kk * 64 + wm + l31) * 16 + half * 8];
            const long long b0 = *(const long long*)&sB[(kk * 128 + wn + l31) * 16 + half * 8];
            const long long b1 = *(const long long*)&sB[(kk * 128 + wn + 32 + l31) * 16 + half * 8];
            acc[0] = __builtin_amdgcn_mfma_f32_32x32x16_fp8_fp8(a0, b0, acc[0], 0, 0, 0);
            acc[1] = __builtin_amdgcn_mfma_f32_32x32x16_fp8_fp8(a0, b1, acc[1], 0, 0, 0);
        }
    }

    // epilogue: scatter into sB (64x128 fp8 = 8KB), then coalesced 16B stores
    __syncthreads();
#pragma unroll
    for (int nn = 0; nn < 2; ++nn) {
        const int lcol = wn + nn * 32 + l31;
#pragma unroll
        for (int q = 0; q < 16; ++q) {
            const int lrow = wm + (q & 3) + 8 * (q >> 2) + 4 * half;
            sB[lrow * 128 + lcol] = enc_fp8(acc[nn][q] * BSCALE_INV);
        }
    }
    __syncthreads();
    fp8_t* outp = xkp + (size_t)kz * P + (size_t)m0 * OUT_F + n0;
#pragma unroll
    for (int s = 0; s < 2; ++s) {
        const int f = (s * 256 + tid) * 16;
        *(int4*)&outp[(size_t)(f >> 7) * OUT_F + (f & 127)] = *(const int4*)&sB[f];
    }
}

// ---------------------------------------------------------------------------
// Update: xk = sum of 4 fp8 partials; softshrink; u update; conv check;
// write next Aeff fp8. One block per row; 8 elements per thread.
// ---------------------------------------------------------------------------
__global__ __launch_bounds__(256)
void update_kernel(const fp8_t* __restrict__ xkp, const fp8_t* __restrict__ Ab8,
                   _Float16* __restrict__ v, _Float16* __restrict__ u,
                   float* __restrict__ enc, fp8_t* __restrict__ Ah,
                   int* __restrict__ solved) {
    const int row = blockIdx.x;
    if (solved[row]) return;
    const int t = threadIdx.x;
    constexpr size_t P = (size_t)BATCH * OUT_F;

    const int c = t * 8;
    const size_t off = (size_t)row * OUT_F + c;
    const int2 q0 = *(const int2*)&xkp[off];
    const int2 q1 = *(const int2*)&xkp[P + off];
    const int2 q2 = *(const int2*)&xkp[2 * P + off];
    const int2 q3 = *(const int2*)&xkp[3 * P + off];
    const half8 u8 = *(const half8*)&u[off];
    const half8 v8 = *(const half8*)&v[off];
    const int2 ab2 = *(const int2*)&Ab8[off];

    float f0[4], f1[4], f2[4], f3[4], g0[4], g1[4], g2[4], g3[4];
    cvt4_fp8(q0.x, f0); cvt4_fp8(q1.x, f1); cvt4_fp8(q2.x, f2); cvt4_fp8(q3.x, f3);
    cvt4_fp8(q0.y, g0); cvt4_fp8(q1.y, g1); cvt4_fp8(q2.y, g2); cvt4_fp8(q3.y, g3);
    float ab0[4], ab1[4];
    cvt4_fp8(ab2.x, ab0); cvt4_fp8(ab2.y, ab1);
    float xs[8], abv[8];
#pragma unroll
    for (int j = 0; j < 4; ++j) {
        xs[j] = f0[j] + f1[j] + f2[j] + f3[j];
        xs[j + 4] = g0[j] + g1[j] + g2[j] + g3[j];
        abv[j] = ab0[j];
        abv[j + 4] = ab1[j];
    }

    float vn_all[8], ae[8];
    half8 vo, uo;
    float dx2 = 0.f, xn2 = 0.f;
#pragma unroll
    for (int j = 0; j < 8; ++j) {
        const float xk = xs[j];
        const float uv = (float)u8[j];
        const float vp = (float)v8[j];
        const float z = xk + uv;
        const float az = fabsf(z) - LAMBD;
        const float vnew = az > 0.f ? copysignf(az, z) : 0.f;
        const float unew = uv + xk - vnew;
        const float d = vnew - vp;
        dx2 += d * d;
        xn2 += vnew * vnew;
        vn_all[j] = vnew;
        vo[j] = (_Float16)vnew;
        uo[j] = (_Float16)unew;
        ae[j] = abv[j] + vnew - unew;
    }
    *(half8*)&v[off] = vo;
    *(half8*)&u[off] = uo;
    int2 ah;
    ah.x = pk4_fp8(ae[0], ae[1], ae[2], ae[3]);
    ah.y = pk4_fp8(ae[4], ae[5], ae[6], ae[7]);
    *(int2*)&Ah[off] = ah;

#pragma unroll
    for (int o = 32; o > 0; o >>= 1) {
        dx2 += __shfl_down(dx2, o);
        xn2 += __shfl_down(xn2, o);
    }
    __shared__ float sdx[4], sxn[4];
    __shared__ float s_conv;
    if ((t & 63) == 0) { sdx[t >> 6] = dx2; sxn[t >> 6] = xn2; }
    __syncthreads();
    if (t == 0) {
        const float dxt = sqrtf(sdx[0] + sdx[1] + sdx[2] + sdx[3]);
        const float xnt = sqrtf(sxn[0] + sxn[1] + sxn[2] + sxn[3]);
        const bool conv = (dxt / xnt) < TOL;   // NaN -> false, matches jnp
        s_conv = conv ? 1.f : 0.f;
        if (conv) solved[row] = 1;
    }
    __syncthreads();
    if (s_conv != 0.f) {
        *(float4*)&enc[off] = make_float4(vn_all[0], vn_all[1], vn_all[2], vn_all[3]);
        *(float4*)&enc[off + 4] = make_float4(vn_all[4], vn_all[5], vn_all[6], vn_all[7]);
    }
}

// ---------------------------------------------------------------------------
extern "C" void kernel_launch(void* const* d_in, const int* in_sizes, int n_in,
                              void* d_out, int out_size, void* d_ws, size_t ws_size,
                              hipStream_t stream) {
    (void)in_sizes; (void)n_in; (void)out_size; (void)ws_size;
    const float* x    = (const float*)d_in[0];   // 1024 x 1024
    const float* w    = (const float*)d_in[1];   // 2048 x 1024
    const float* Minv = (const float*)d_in[2];   // 2048 x 2048

    float* enc = (float*)d_out;                  // 1024 x 2048
    float* dec = enc + (size_t)BATCH * OUT_F;    // 1024 x 1024

    constexpr size_t P = (size_t)BATCH * OUT_F;  // 2M elements
    fp8_t* Ab8 = (fp8_t*)d_ws;                   // P fp8
    _Float16* v   = (_Float16*)(Ab8 + P);        // P f16
    _Float16* u   = v + P;                       // P f16
    _Float16* xh  = u + P;                       // 1M f16
    _Float16* wh  = xh + (size_t)BATCH * IN_F;   // 2M f16
    _Float16* whT = wh + (size_t)OUT_F * IN_F;   // 2M f16
    _Float16* ench = whT + (size_t)IN_F * OUT_F; // P f16
    fp8_t* Ah  = (fp8_t*)(ench + P);             // P fp8
    fp8_t* xkp = Ah + P;                         // 4P fp8
    fp8_t* BhT = xkp + 4 * P;                    // OUT_F^2 fp8 (4MB)
    int* solved = (int*)(BhT + (size_t)OUT_F * OUT_F);

    {
        const int n = BATCH * OUT_F / 4;
        init_kernel<<<(n + 255) / 256, 256, 0, stream>>>(
            (float4*)v, (float4*)u, (float4*)enc, solved);
    }

    split_b_kernel<<<dim3(OUT_F / 32, OUT_F / 32), 256, 0, stream>>>(Minv, BhT);

    cast_f16_kernel<<<(BATCH * IN_F / 4 + 255) / 256, 256, 0, stream>>>(x, xh, BATCH * IN_F);
    cast_f16_kernel<<<(OUT_F * IN_F / 4 + 255) / 256, 256, 0, stream>>>(w, wh, OUT_F * IN_F);
    transpose_w_kernel<<<dim3(IN_F / 32, OUT_F / 32), 256, 0, stream>>>(w, whT);

    // Ab = x @ w^T (MFMA fp16) -> Ab8 fp8 + initial Aeff fp8
    mfma_nt_ab<<<dim3(OUT_F / 128, BATCH / 128), 256, 0, stream>>>(
        xh, wh, Ab8, Ah, OUT_F, IN_F);

    for (int it = 0; it < MAX_ITERS; ++it) {
        xk_mfma<<<dim3(OUT_F / 128, BATCH / 64, KSPLIT), 256, 0, stream>>>(
            Ah, BhT, xkp, solved);
        update_kernel<<<BATCH, 256, 0, stream>>>(xkp, Ab8, v, u, enc, Ah, solved);
    }

    // decoded = encoded @ w (MFMA fp16)
    cast_f16_kernel<<<(BATCH * OUT_F / 4 + 255) / 256, 256, 0, stream>>>(enc, ench, BATCH * OUT_F);
    mfma_nn_dec<<<dim3(IN_F / 128, BATCH / 128), 256, 0, stream>>>(
        ench, whT, dec, IN_F, OUT_F);
}

// Round 13
// 2222.124 us; speedup vs baseline: 8.5579x; 1.1736x over previous
//
#include <hip/hip_runtime.h>
#include <math.h>

#define BATCH 1024
#define IN_F  1024
#define OUT_F 2048
#define LAMBD 0.2f
#define TOL   1e-4f
#define MAX_ITERS 100

#define KSPLIT 4
#define KCHUNK (OUT_F / KSPLIT)   // 512
#define BSCALE 32.0f
#define BSCALE_INV 0.03125f

typedef _Float16 half8 __attribute__((ext_vector_type(8)));
typedef _Float16 half4 __attribute__((ext_vector_type(4)));
typedef float    floatx16 __attribute__((ext_vector_type(16)));
typedef unsigned char fp8_t;

#define GLOAD_LDS16(g, l) __builtin_amdgcn_global_load_lds(              \
    (const __attribute__((address_space(1))) void*)(g),                  \
    (__attribute__((address_space(3))) void*)(l), 16, 0, 0)

// fp8 e4m3 (OCP on gfx950) HW converts
__device__ inline int pk4_fp8(float a, float b, float c, float d) {
    int w = __builtin_amdgcn_cvt_pk_fp8_f32(a, b, 0, false);
    w = __builtin_amdgcn_cvt_pk_fp8_f32(c, d, w, true);
    return w;
}
__device__ inline fp8_t enc_fp8(float a) {
    return (fp8_t)(__builtin_amdgcn_cvt_pk_fp8_f32(a, a, 0, false) & 0xff);
}
// byte-selector must be a literal constant -> expand all four
__device__ inline void cvt4_fp8(int w, float o[4]) {
    o[0] = __builtin_amdgcn_cvt_f32_fp8(w, 0);
    o[1] = __builtin_amdgcn_cvt_f32_fp8(w, 1);
    o[2] = __builtin_amdgcn_cvt_f32_fp8(w, 2);
    o[3] = __builtin_amdgcn_cvt_f32_fp8(w, 3);
}

// ---------------------------------------------------------------------------
// init: zero v,u (fp16), enc (fp32 out), solved flags
// ---------------------------------------------------------------------------
__global__ void init_kernel(float4* __restrict__ v16, float4* __restrict__ u16,
                            float4* __restrict__ enc, int* __restrict__ solved) {
    const int i = blockIdx.x * blockDim.x + threadIdx.x;
    const float4 z = make_float4(0.f, 0.f, 0.f, 0.f);
    const int nh = BATCH * OUT_F / 8;
    const int n4 = BATCH * OUT_F / 4;
    if (i < nh) { v16[i] = z; u16[i] = z; }
    if (i < n4) enc[i] = z;
    if (i < BATCH) solved[i] = 0;
}

// ---------------------------------------------------------------------------
__global__ __launch_bounds__(256)
void cast_f16_kernel(const float* __restrict__ in, _Float16* __restrict__ out, int n) {
    const int i = (blockIdx.x * 256 + threadIdx.x) * 4;
    if (i < n) {
        const float4 f = *(const float4*)&in[i];
        half4 h;
        h[0] = (_Float16)f.x; h[1] = (_Float16)f.y;
        h[2] = (_Float16)f.z; h[3] = (_Float16)f.w;
        *(half4*)&out[i] = h;
    }
}

// ---------------------------------------------------------------------------
__global__ __launch_bounds__(256)
void transpose_w_kernel(const float* __restrict__ W, _Float16* __restrict__ WT) {
    __shared__ float tile[32][33];
    const int tid = threadIdx.x;
    const int row0 = blockIdx.y * 32;
    const int col0 = blockIdx.x * 32;
    const int r = tid >> 3;
    const int c4 = (tid & 7) * 4;
    const float4 b4 = *(const float4*)&W[(size_t)(row0 + r) * IN_F + col0 + c4];
    tile[r][c4 + 0] = b4.x; tile[r][c4 + 1] = b4.y;
    tile[r][c4 + 2] = b4.z; tile[r][c4 + 3] = b4.w;
    __syncthreads();
    half4 h;
#pragma unroll
    for (int j = 0; j < 4; ++j) h[j] = (_Float16)tile[c4 + j][r];
    *(half4*)&WT[(size_t)(col0 + r) * OUT_F + row0 + c4] = h;
}

// ---------------------------------------------------------------------------
// Transpose + fp8-cast (x32) M_inv (2048x2048 fp32 [k][n]) -> BhT fp8 [n][k].
// ---------------------------------------------------------------------------
__global__ __launch_bounds__(256)
void split_b_kernel(const float* __restrict__ B, fp8_t* __restrict__ BhT) {
    __shared__ float tile[32][33];
    const int tid = threadIdx.x;
    const int k0 = blockIdx.y * 32;
    const int n0 = blockIdx.x * 32;
    const int r = tid >> 3;
    const int c4 = (tid & 7) * 4;
    const float4 b4 = *(const float4*)&B[(size_t)(k0 + r) * OUT_F + n0 + c4];
    tile[r][c4 + 0] = b4.x; tile[r][c4 + 1] = b4.y;
    tile[r][c4 + 2] = b4.z; tile[r][c4 + 3] = b4.w;
    __syncthreads();
    const int w = pk4_fp8(tile[c4 + 0][r] * BSCALE, tile[c4 + 1][r] * BSCALE,
                          tile[c4 + 2][r] * BSCALE, tile[c4 + 3][r] * BSCALE);
    *(int*)&BhT[(size_t)(n0 + r) * OUT_F + k0 + c4] = w;
}

// ---------------------------------------------------------------------------
// fp16 MFMA NT GEMM (one-shot): Ab = x @ w^T -> Ab8 fp8 (persistent) +
// initial Aeff fp8 (identical, v=u=0). 128x128 tile, BK=32.
// ---------------------------------------------------------------------------
__global__ __launch_bounds__(256)
void mfma_nt_ab(const _Float16* __restrict__ A, const _Float16* __restrict__ B,
                fp8_t* __restrict__ Ab8, fp8_t* __restrict__ Ah,
                int N, int K) {
    __shared__ _Float16 sA[128 * 32];
    __shared__ _Float16 sB[128 * 32];
    const int tid = threadIdx.x;
    const int m0 = blockIdx.y * 128;
    const int n0 = blockIdx.x * 128;
    const int wv = tid >> 6, ln = tid & 63;
    const int half = ln >> 5, l31 = ln & 31;
    const int wm = (wv >> 1) * 64, wn = (wv & 1) * 64;
    const int r0 = tid >> 2, koff = (tid & 3) * 8;
    const size_t ga0 = (size_t)(m0 + r0) * K + koff;
    const size_t ga1 = (size_t)(m0 + r0 + 64) * K + koff;
    const size_t gb0 = (size_t)(n0 + r0) * K + koff;
    const size_t gb1 = (size_t)(n0 + r0 + 64) * K + koff;
    const int ldst0 = tid * 8, ldst1 = (256 + tid) * 8;

    floatx16 acc[2][2];
#pragma unroll
    for (int a = 0; a < 2; ++a)
#pragma unroll
        for (int b = 0; b < 2; ++b)
#pragma unroll
            for (int q = 0; q < 16; ++q) acc[a][b][q] = 0.f;

    for (int k = 0; k < K; k += 32) {
        __syncthreads();
        GLOAD_LDS16(A + ga0 + k, sA + ldst0);
        GLOAD_LDS16(A + ga1 + k, sA + ldst1);
        GLOAD_LDS16(B + gb0 + k, sB + ldst0);
        GLOAD_LDS16(B + gb1 + k, sB + ldst1);
        __syncthreads();
#pragma unroll
        for (int kk = 0; kk < 2; ++kk) {
            const int ko = kk * 16 + half * 8;
            const half8 a0 = *(const half8*)&sA[(wm + l31) * 32 + ko];
            const half8 a1 = *(const half8*)&sA[(wm + 32 + l31) * 32 + ko];
            const half8 b0 = *(const half8*)&sB[(wn + l31) * 32 + ko];
            const half8 b1 = *(const half8*)&sB[(wn + 32 + l31) * 32 + ko];
            acc[0][0] = __builtin_amdgcn_mfma_f32_32x32x16_f16(a0, b0, acc[0][0], 0, 0, 0);
            acc[0][1] = __builtin_amdgcn_mfma_f32_32x32x16_f16(a0, b1, acc[0][1], 0, 0, 0);
            acc[1][0] = __builtin_amdgcn_mfma_f32_32x32x16_f16(a1, b0, acc[1][0], 0, 0, 0);
            acc[1][1] = __builtin_amdgcn_mfma_f32_32x32x16_f16(a1, b1, acc[1][1], 0, 0, 0);
        }
    }
#pragma unroll
    for (int mm = 0; mm < 2; ++mm)
#pragma unroll
        for (int nn = 0; nn < 2; ++nn) {
            const int col = n0 + wn + nn * 32 + l31;
#pragma unroll
            for (int q = 0; q < 16; ++q) {
                const int row = m0 + wm + mm * 32 + (q & 3) + 8 * (q >> 2) + 4 * half;
                const size_t o = (size_t)row * N + col;
                const fp8_t e = enc_fp8(acc[mm][nn][q]);
                Ab8[o] = e;
                Ah[o] = e;     // initial Aeff (v=u=0)
            }
        }
}

// ---------------------------------------------------------------------------
// fp16 MFMA NT GEMM (one-shot): dec = enc @ w via A=ench, B=whT (both K-major)
// ---------------------------------------------------------------------------
__global__ __launch_bounds__(256)
void mfma_nn_dec(const _Float16* __restrict__ A, const _Float16* __restrict__ B,
                 float* __restrict__ C, int N, int K) {
    __shared__ _Float16 sA[128 * 32];
    __shared__ _Float16 sB[128 * 32];
    const int tid = threadIdx.x;
    const int m0 = blockIdx.y * 128;
    const int n0 = blockIdx.x * 128;
    const int wv = tid >> 6, ln = tid & 63;
    const int half = ln >> 5, l31 = ln & 31;
    const int wm = (wv >> 1) * 64, wn = (wv & 1) * 64;
    const int r0 = tid >> 2, koff = (tid & 3) * 8;
    const size_t ga0 = (size_t)(m0 + r0) * K + koff;
    const size_t ga1 = (size_t)(m0 + r0 + 64) * K + koff;
    const size_t gb0 = (size_t)(n0 + r0) * K + koff;
    const size_t gb1 = (size_t)(n0 + r0 + 64) * K + koff;
    const int ldst0 = tid * 8, ldst1 = (256 + tid) * 8;

    floatx16 acc[2][2];
#pragma unroll
    for (int a = 0; a < 2; ++a)
#pragma unroll
        for (int b = 0; b < 2; ++b)
#pragma unroll
            for (int q = 0; q < 16; ++q) acc[a][b][q] = 0.f;

    for (int k = 0; k < K; k += 32) {
        __syncthreads();
        GLOAD_LDS16(A + ga0 + k, sA + ldst0);
        GLOAD_LDS16(A + ga1 + k, sA + ldst1);
        GLOAD_LDS16(B + gb0 + k, sB + ldst0);
        GLOAD_LDS16(B + gb1 + k, sB + ldst1);
        __syncthreads();
#pragma unroll
        for (int kk = 0; kk < 2; ++kk) {
            const int ko = kk * 16 + half * 8;
            const half8 a0 = *(const half8*)&sA[(wm + l31) * 32 + ko];
            const half8 a1 = *(const half8*)&sA[(wm + 32 + l31) * 32 + ko];
            const half8 b0 = *(const half8*)&sB[(wn + l31) * 32 + ko];
            const half8 b1 = *(const half8*)&sB[(wn + 32 + l31) * 32 + ko];
            acc[0][0] = __builtin_amdgcn_mfma_f32_32x32x16_f16(a0, b0, acc[0][0], 0, 0, 0);
            acc[0][1] = __builtin_amdgcn_mfma_f32_32x32x16_f16(a0, b1, acc[0][1], 0, 0, 0);
            acc[1][0] = __builtin_amdgcn_mfma_f32_32x32x16_f16(a1, b0, acc[1][0], 0, 0, 0);
            acc[1][1] = __builtin_amdgcn_mfma_f32_32x32x16_f16(a1, b1, acc[1][1], 0, 0, 0);
        }
    }
#pragma unroll
    for (int mm = 0; mm < 2; ++mm)
#pragma unroll
        for (int nn = 0; nn < 2; ++nn) {
            const int col = n0 + wn + nn * 32 + l31;
#pragma unroll
            for (int q = 0; q < 16; ++q) {
                const int row = m0 + wm + mm * 32 + (q & 3) + 8 * (q >> 2) + 4 * half;
                C[(size_t)row * N + col] = acc[mm][nn][q];
            }
        }
}

// ---------------------------------------------------------------------------
// fp8 MFMA GEMM (R9-proven config): xk_part[kz] = Aeff @ (32*Minv) / 32.
// 128x128 tile, BK=64, KSPLIT=4, grid (16,8,4)=512 blocks = 2/CU.
// Column-chunk LDS staging (conflict-free); LDS-transpose epilogue for
// coalesced 16B xkp stores.
// ---------------------------------------------------------------------------
__global__ __launch_bounds__(256)
void xk_mfma(const fp8_t* __restrict__ Ah, const fp8_t* __restrict__ BhT,
             fp8_t* __restrict__ xkp, const int* __restrict__ solved) {
    __shared__ fp8_t smem[16384];
    fp8_t* sA = smem;           // 8KB
    fp8_t* sB = smem + 8192;    // 8KB
    const int tid = threadIdx.x;
    const int m0 = blockIdx.y * 128;
    const int n0 = blockIdx.x * 128;
    const int kz = blockIdx.z;
    constexpr size_t P = (size_t)BATCH * OUT_F;

    __shared__ int s_active;
    if (tid == 0) s_active = 0;
    __syncthreads();
    if (tid < 128 && solved[m0 + tid] == 0) s_active = 1;   // benign race
    __syncthreads();
    if (!s_active) return;

    const int wv = tid >> 6;
    const int ln = tid & 63;
    const int half = ln >> 5;
    const int l31 = ln & 31;
    const int wm = (wv >> 1) * 64;
    const int wn = (wv & 1) * 64;

    const int r = tid & 127;
    const int c0 = tid >> 7;           // 0 or 1
    const fp8_t* gA = Ah  + (size_t)(m0 + r) * OUT_F + kz * KCHUNK;
    const fp8_t* gB = BhT + (size_t)(n0 + r) * OUT_F + kz * KCHUNK;
    fp8_t* lA0 = sA + (c0 * 128 + r) * 16;
    fp8_t* lA1 = sA + ((c0 + 2) * 128 + r) * 16;
    fp8_t* lB0 = sB + (c0 * 128 + r) * 16;
    fp8_t* lB1 = sB + ((c0 + 2) * 128 + r) * 16;

    floatx16 acc[2][2];
#pragma unroll
    for (int a = 0; a < 2; ++a)
#pragma unroll
        for (int b = 0; b < 2; ++b)
#pragma unroll
            for (int q = 0; q < 16; ++q) acc[a][b][q] = 0.f;

    const int ao0 = (wm + l31) * 16 + half * 8;
    const int ao1 = (wm + 32 + l31) * 16 + half * 8;
    const int bo0 = (wn + l31) * 16 + half * 8;
    const int bo1 = (wn + 32 + l31) * 16 + half * 8;

    for (int k = 0; k < KCHUNK; k += 64) {
        __syncthreads();
        GLOAD_LDS16(gA + k + c0 * 16, lA0);
        GLOAD_LDS16(gA + k + (c0 + 2) * 16, lA1);
        GLOAD_LDS16(gB + k + c0 * 16, lB0);
        GLOAD_LDS16(gB + k + (c0 + 2) * 16, lB1);
        __syncthreads();

#pragma unroll
        for (int kk = 0; kk < 4; ++kk) {
            const int cb = kk * 2048;
            const long long a0 = *(const long long*)&sA[cb + ao0];
            const long long a1 = *(const long long*)&sA[cb + ao1];
            const long long b0 = *(const long long*)&sB[cb + bo0];
            const long long b1 = *(const long long*)&sB[cb + bo1];
            acc[0][0] = __builtin_amdgcn_mfma_f32_32x32x16_fp8_fp8(a0, b0, acc[0][0], 0, 0, 0);
            acc[0][1] = __builtin_amdgcn_mfma_f32_32x32x16_fp8_fp8(a0, b1, acc[0][1], 0, 0, 0);
            acc[1][0] = __builtin_amdgcn_mfma_f32_32x32x16_fp8_fp8(a1, b0, acc[1][0], 0, 0, 0);
            acc[1][1] = __builtin_amdgcn_mfma_f32_32x32x16_fp8_fp8(a1, b1, acc[1][1], 0, 0, 0);
        }
    }

    // epilogue: scatter fp8 results into LDS tile, then coalesced 16B stores
    __syncthreads();
#pragma unroll
    for (int mm = 0; mm < 2; ++mm)
#pragma unroll
        for (int nn = 0; nn < 2; ++nn) {
            const int lcol = wn + nn * 32 + l31;
#pragma unroll
            for (int q = 0; q < 16; ++q) {
                const int lrow = wm + mm * 32 + (q & 3) + 8 * (q >> 2) + 4 * half;
                smem[lrow * 128 + lcol] = enc_fp8(acc[mm][nn][q] * BSCALE_INV);
            }
        }
    __syncthreads();
    fp8_t* outp = xkp + kz * P + (size_t)m0 * OUT_F + n0;
#pragma unroll
    for (int s = 0; s < 4; ++s) {
        const int f = (s * 256 + tid) * 16;
        *(int4*)&outp[(size_t)(f >> 7) * OUT_F + (f & 127)] = *(const int4*)&smem[f];
    }
}

// ---------------------------------------------------------------------------
// Update: xk = sum of 4 fp8 partials; softshrink; u update; conv check;
// write next Aeff fp8. One block per row; 8 elements per thread.
// ---------------------------------------------------------------------------
__global__ __launch_bounds__(256)
void update_kernel(const fp8_t* __restrict__ xkp, const fp8_t* __restrict__ Ab8,
                   _Float16* __restrict__ v, _Float16* __restrict__ u,
                   float* __restrict__ enc, fp8_t* __restrict__ Ah,
                   int* __restrict__ solved) {
    const int row = blockIdx.x;
    if (solved[row]) return;
    const int t = threadIdx.x;
    constexpr size_t P = (size_t)BATCH * OUT_F;

    const int c = t * 8;
    const size_t off = (size_t)row * OUT_F + c;
    const int2 q0 = *(const int2*)&xkp[off];
    const int2 q1 = *(const int2*)&xkp[P + off];
    const int2 q2 = *(const int2*)&xkp[2 * P + off];
    const int2 q3 = *(const int2*)&xkp[3 * P + off];
    const half8 u8 = *(const half8*)&u[off];
    const half8 v8 = *(const half8*)&v[off];
    const int2 ab2 = *(const int2*)&Ab8[off];

    float f0[4], f1[4], f2[4], f3[4], g0[4], g1[4], g2[4], g3[4];
    cvt4_fp8(q0.x, f0); cvt4_fp8(q1.x, f1); cvt4_fp8(q2.x, f2); cvt4_fp8(q3.x, f3);
    cvt4_fp8(q0.y, g0); cvt4_fp8(q1.y, g1); cvt4_fp8(q2.y, g2); cvt4_fp8(q3.y, g3);
    float ab0[4], ab1[4];
    cvt4_fp8(ab2.x, ab0); cvt4_fp8(ab2.y, ab1);
    float xs[8], abv[8];
#pragma unroll
    for (int j = 0; j < 4; ++j) {
        xs[j] = f0[j] + f1[j] + f2[j] + f3[j];
        xs[j + 4] = g0[j] + g1[j] + g2[j] + g3[j];
        abv[j] = ab0[j];
        abv[j + 4] = ab1[j];
    }

    float vn_all[8], ae[8];
    half8 vo, uo;
    float dx2 = 0.f, xn2 = 0.f;
#pragma unroll
    for (int j = 0; j < 8; ++j) {
        const float xk = xs[j];
        const float uv = (float)u8[j];
        const float vp = (float)v8[j];
        const float z = xk + uv;
        const float az = fabsf(z) - LAMBD;
        const float vnew = az > 0.f ? copysignf(az, z) : 0.f;
        const float unew = uv + xk - vnew;
        const float d = vnew - vp;
        dx2 += d * d;
        xn2 += vnew * vnew;
        vn_all[j] = vnew;
        vo[j] = (_Float16)vnew;
        uo[j] = (_Float16)unew;
        ae[j] = abv[j] + vnew - unew;
    }
    *(half8*)&v[off] = vo;
    *(half8*)&u[off] = uo;
    int2 ah;
    ah.x = pk4_fp8(ae[0], ae[1], ae[2], ae[3]);
    ah.y = pk4_fp8(ae[4], ae[5], ae[6], ae[7]);
    *(int2*)&Ah[off] = ah;

#pragma unroll
    for (int o = 32; o > 0; o >>= 1) {
        dx2 += __shfl_down(dx2, o);
        xn2 += __shfl_down(xn2, o);
    }
    __shared__ float sdx[4], sxn[4];
    __shared__ float s_conv;
    if ((t & 63) == 0) { sdx[t >> 6] = dx2; sxn[t >> 6] = xn2; }
    __syncthreads();
    if (t == 0) {
        const float dxt = sqrtf(sdx[0] + sdx[1] + sdx[2] + sdx[3]);
        const float xnt = sqrtf(sxn[0] + sxn[1] + sxn[2] + sxn[3]);
        const bool conv = (dxt / xnt) < TOL;   // NaN -> false, matches jnp
        s_conv = conv ? 1.f : 0.f;
        if (conv) solved[row] = 1;
    }
    __syncthreads();
    if (s_conv != 0.f) {
        *(float4*)&enc[off] = make_float4(vn_all[0], vn_all[1], vn_all[2], vn_all[3]);
        *(float4*)&enc[off + 4] = make_float4(vn_all[4], vn_all[5], vn_all[6], vn_all[7]);
    }
}

// ---------------------------------------------------------------------------
extern "C" void kernel_launch(void* const* d_in, const int* in_sizes, int n_in,
                              void* d_out, int out_size, void* d_ws, size_t ws_size,
                              hipStream_t stream) {
    (void)in_sizes; (void)n_in; (void)out_size; (void)ws_size;
    const float* x    = (const float*)d_in[0];   // 1024 x 1024
    const float* w    = (const float*)d_in[1];   // 2048 x 1024
    const float* Minv = (const float*)d_in[2];   // 2048 x 2048

    float* enc = (float*)d_out;                  // 1024 x 2048
    float* dec = enc + (size_t)BATCH * OUT_F;    // 1024 x 1024

    constexpr size_t P = (size_t)BATCH * OUT_F;  // 2M elements
    fp8_t* Ab8 = (fp8_t*)d_ws;                   // P fp8
    _Float16* v   = (_Float16*)(Ab8 + P);        // P f16
    _Float16* u   = v + P;                       // P f16
    _Float16* xh  = u + P;                       // 1M f16
    _Float16* wh  = xh + (size_t)BATCH * IN_F;   // 2M f16
    _Float16* whT = wh + (size_t)OUT_F * IN_F;   // 2M f16
    _Float16* ench = whT + (size_t)IN_F * OUT_F; // P f16
    fp8_t* Ah  = (fp8_t*)(ench + P);             // P fp8
    fp8_t* xkp = Ah + P;                         // 4P fp8
    fp8_t* BhT = xkp + 4 * P;                    // OUT_F^2 fp8 (4MB)
    int* solved = (int*)(BhT + (size_t)OUT_F * OUT_F);

    {
        const int n = BATCH * OUT_F / 4;
        init_kernel<<<(n + 255) / 256, 256, 0, stream>>>(
            (float4*)v, (float4*)u, (float4*)enc, solved);
    }

    split_b_kernel<<<dim3(OUT_F / 32, OUT_F / 32), 256, 0, stream>>>(Minv, BhT);

    cast_f16_kernel<<<(BATCH * IN_F / 4 + 255) / 256, 256, 0, stream>>>(x, xh, BATCH * IN_F);
    cast_f16_kernel<<<(OUT_F * IN_F / 4 + 255) / 256, 256, 0, stream>>>(w, wh, OUT_F * IN_F);
    transpose_w_kernel<<<dim3(IN_F / 32, OUT_F / 32), 256, 0, stream>>>(w, whT);

    // Ab = x @ w^T (MFMA fp16) -> Ab8 fp8 + initial Aeff fp8
    mfma_nt_ab<<<dim3(OUT_F / 128, BATCH / 128), 256, 0, stream>>>(
        xh, wh, Ab8, Ah, OUT_F, IN_F);

    for (int it = 0; it < MAX_ITERS; ++it) {
        xk_mfma<<<dim3(OUT_F / 128, BATCH / 128, KSPLIT), 256, 0, stream>>>(
            Ah, BhT, xkp, solved);
        update_kernel<<<BATCH, 256, 0, stream>>>(xkp, Ab8, v, u, enc, Ah, solved);
    }

    // decoded = encoded @ w (MFMA fp16)
    cast_f16_kernel<<<(BATCH * OUT_F / 4 + 255) / 256, 256, 0, stream>>>(enc, ench, BATCH * OUT_F);
    mfma_nn_dec<<<dim3(IN_F / 128, BATCH / 128), 256, 0, stream>>>(
        ench, whT, dec, IN_F, OUT_F);
}